// Round 1
// baseline (757.057 us; speedup 1.0000x reference)
//
#include <hip/hip_runtime.h>
#include <hip/hip_bf16.h>

#define D_IN 128
#define D_OUT 64
#define BN_EPS 1e-5f

// ---------------- CSR construction ----------------

__global__ void hist_kernel(const int* __restrict__ dst, int* __restrict__ cnt, int E) {
    int i = blockIdx.x * blockDim.x + threadIdx.x;
    if (i < E) atomicAdd(&cnt[dst[i]], 1);
}

// single-block exclusive scan of cnt[0..n) -> offs[0..n]
__global__ void scan_kernel(const int* __restrict__ cnt, int* __restrict__ offs, int n) {
    __shared__ int wsum[16];
    __shared__ int carry_s;
    int tid = threadIdx.x;
    int lane = tid & 63, wid = tid >> 6;
    if (tid == 0) carry_s = 0;
    __syncthreads();
    const int CH = 4096; // 1024 threads * 4 elems
    for (int base = 0; base < n; base += CH) {
        int i0 = base + tid * 4;
        int v[4];
#pragma unroll
        for (int j = 0; j < 4; j++) { int i = i0 + j; v[j] = (i < n) ? cnt[i] : 0; }
        int tsum = v[0] + v[1] + v[2] + v[3];
        int sc = tsum;
#pragma unroll
        for (int off = 1; off < 64; off <<= 1) {
            int t = __shfl_up(sc, off);
            if (lane >= off) sc += t;
        }
        if (lane == 63) wsum[wid] = sc;
        __syncthreads();
        int wbase = 0;
        for (int w = 0; w < 16; w++) if (w < wid) wbase += wsum[w];
        int carry = carry_s;
        __syncthreads();
        int run = carry + wbase + sc - tsum; // exclusive prefix for first elem
#pragma unroll
        for (int j = 0; j < 4; j++) {
            int i = i0 + j;
            if (i < n) offs[i] = run;
            run += v[j];
        }
        if (tid == 1023) carry_s = carry + wbase + sc;
        __syncthreads();
    }
    if (tid == 0) offs[n] = carry_s;
}

__global__ void scatter_kernel(const int* __restrict__ src, const int* __restrict__ dst,
                               int* __restrict__ cursor, int* __restrict__ sorted_src, int E) {
    int i = blockIdx.x * blockDim.x + threadIdx.x;
    if (i < E) {
        int p = atomicAdd(&cursor[dst[i]], 1);
        sorted_src[p] = src[i];
    }
}

// ---------------- GEMM: C[M][TN] = A[M][128] @ W[128][TN] ----------------

template <int TN>
__global__ __launch_bounds__(256) void gemm_kernel(const float* __restrict__ A,
                                                   const float* __restrict__ W,
                                                   float* __restrict__ C, int M) {
    const int BM = 64, BK = 32;
    const int TC = TN / 16; // cols per thread (8 or 4)
    __shared__ float As[BM][BK + 1];
    __shared__ float Bs[BK][TN];
    int tid = threadIdx.x;
    int row0 = blockIdx.x * BM;
    int tr = tid / 16; // 0..15 -> rows tr*4 .. tr*4+3
    int tc = tid % 16; // cols tc*TC ..

    float acc[4][TC];
#pragma unroll
    for (int i = 0; i < 4; i++)
#pragma unroll
        for (int j = 0; j < TC; j++) acc[i][j] = 0.f;

    for (int k0 = 0; k0 < D_IN; k0 += BK) {
        // A tile: 64x32 floats = 512 float4 loads over 256 threads
#pragma unroll
        for (int l = tid; l < BM * BK / 4; l += 256) {
            int r = l / (BK / 4);
            int c = (l % (BK / 4)) * 4;
            int gr = row0 + r;
            float4 v = make_float4(0.f, 0.f, 0.f, 0.f);
            if (gr < M) v = *(const float4*)&A[(size_t)gr * D_IN + k0 + c];
            As[r][c] = v.x; As[r][c + 1] = v.y; As[r][c + 2] = v.z; As[r][c + 3] = v.w;
        }
        // B tile: 32 x TN
#pragma unroll
        for (int l = tid; l < BK * TN / 4; l += 256) {
            int r = l / (TN / 4);
            int c = (l % (TN / 4)) * 4;
            *(float4*)&Bs[r][c] = *(const float4*)&W[(size_t)(k0 + r) * TN + c];
        }
        __syncthreads();
#pragma unroll
        for (int k = 0; k < BK; k++) {
            float a[4];
#pragma unroll
            for (int i = 0; i < 4; i++) a[i] = As[tr * 4 + i][k];
            float b[TC];
#pragma unroll
            for (int j = 0; j < TC; j++) b[j] = Bs[k][tc * TC + j];
#pragma unroll
            for (int i = 0; i < 4; i++)
#pragma unroll
                for (int j = 0; j < TC; j++) acc[i][j] += a[i] * b[j];
        }
        __syncthreads();
    }
#pragma unroll
    for (int i = 0; i < 4; i++) {
        int gr = row0 + tr * 4 + i;
        if (gr < M) {
#pragma unroll
            for (int j = 0; j < TC; j += 4) {
                *(float4*)&C[(size_t)gr * TN + tc * TC + j] =
                    make_float4(acc[i][j], acc[i][j + 1], acc[i][j + 2], acc[i][j + 3]);
            }
        }
    }
}

// ---------------- aggregation: H[node] += mean_neighbors(Y) + bias ----------------

template <int D>
__global__ void agg_kernel(const float* __restrict__ Y, const int* __restrict__ offs,
                           const int* __restrict__ sorted_src, const float* __restrict__ bias,
                           float* __restrict__ H) {
    int node = blockIdx.x;
    int t = threadIdx.x; // D threads
    int s0 = offs[node], s1 = offs[node + 1];
    float acc = 0.f;
    for (int k = s0; k < s1; k++) {
        int s = sorted_src[k];
        acc += Y[(size_t)s * D + t];
    }
    float inv = 1.0f / fmaxf((float)(s1 - s0), 1.0f);
    H[(size_t)node * D + t] += acc * inv + bias[t];
}

// ---------------- BatchNorm ----------------

__global__ void bn_stats_kernel(const float* __restrict__ H, float* __restrict__ stats, int M) {
    int col = threadIdx.x; // 128
    float s = 0.f, s2 = 0.f;
    for (int r = blockIdx.x; r < M; r += gridDim.x) {
        float v = H[(size_t)r * D_IN + col];
        s += v;
        s2 += v * v;
    }
    atomicAdd(&stats[col], s);
    atomicAdd(&stats[D_IN + col], s2);
}

__global__ void bn_apply_kernel(float* __restrict__ H, const float* __restrict__ stats,
                                const float* __restrict__ gamma, const float* __restrict__ beta,
                                int M) {
    int idx = blockIdx.x * blockDim.x + threadIdx.x;
    if (idx >= M * D_IN) return;
    int col = idx & (D_IN - 1);
    float invM = 1.0f / (float)M;
    float mu = stats[col] * invM;
    float var = stats[D_IN + col] * invM - mu * mu;
    float v = (H[idx] - mu) * rsqrtf(var + BN_EPS) * gamma[col] + beta[col];
    H[idx] = fmaxf(v, 0.f);
}

// ---------------- log_softmax over rows of 64 ----------------

__global__ void lsm_kernel(const float* __restrict__ H, float* __restrict__ out, int M) {
    int node = blockIdx.x * (blockDim.x / 64) + (threadIdx.x >> 6);
    int lane = threadIdx.x & 63;
    if (node >= M) return;
    float v = H[(size_t)node * D_OUT + lane];
    float m = v;
#pragma unroll
    for (int off = 32; off; off >>= 1) m = fmaxf(m, __shfl_xor(m, off));
    float e = expf(v - m);
    float s = e;
#pragma unroll
    for (int off = 32; off; off >>= 1) s += __shfl_xor(s, off);
    out[(size_t)node * D_OUT + lane] = (v - m) - logf(s);
}

// ---------------- launch ----------------

extern "C" void kernel_launch(void* const* d_in, const int* in_sizes, int n_in,
                              void* d_out, int out_size, void* d_ws, size_t ws_size,
                              hipStream_t stream) {
    const float* x   = (const float*)d_in[0];
    const int*   ei  = (const int*)d_in[1];
    const float* Wl0 = (const float*)d_in[2];
    const float* Wr0 = (const float*)d_in[3];
    const float* b0  = (const float*)d_in[4];
    const float* g0  = (const float*)d_in[5];
    const float* be0 = (const float*)d_in[6];
    const float* Wl1 = (const float*)d_in[7];
    const float* Wr1 = (const float*)d_in[8];
    const float* b1  = (const float*)d_in[9];
    const float* g1  = (const float*)d_in[10];
    const float* be1 = (const float*)d_in[11];
    const float* Wl2 = (const float*)d_in[12];
    const float* Wr2 = (const float*)d_in[13];
    const float* b2  = (const float*)d_in[14];

    const int N = in_sizes[0] / D_IN;   // 50000
    const int E = in_sizes[1] / 2;      // 800000

    float* Y  = (float*)d_ws;
    float* H1 = Y + (size_t)N * D_IN;
    float* H2 = H1 + (size_t)N * D_IN;
    int* cnt    = (int*)(H2 + (size_t)N * D_IN);
    int* offs   = cnt + N;
    int* cursor = offs + N + 1;
    int* sorted = cursor + N;
    float* stats = (float*)(sorted + E);

    // ---- CSR build (once, reused by all 3 layers) ----
    hipMemsetAsync(cnt, 0, (size_t)N * sizeof(int), stream);
    hist_kernel<<<(E + 255) / 256, 256, 0, stream>>>(ei + E, cnt, E);
    scan_kernel<<<1, 1024, 0, stream>>>(cnt, offs, N);
    hipMemcpyAsync(cursor, offs, (size_t)N * sizeof(int), hipMemcpyDeviceToDevice, stream);
    scatter_kernel<<<(E + 255) / 256, 256, 0, stream>>>(ei, ei + E, cursor, sorted, E);

    const int gb = (N + 63) / 64;

    // ---- layer 0: h = mean(x@Wl0) + x@Wr0 + b0 ; BN+ReLU ----
    gemm_kernel<128><<<gb, 256, 0, stream>>>(x, Wl0, Y, N);
    gemm_kernel<128><<<gb, 256, 0, stream>>>(x, Wr0, H1, N);
    agg_kernel<128><<<N, 128, 0, stream>>>(Y, offs, sorted, b0, H1);
    hipMemsetAsync(stats, 0, 256 * sizeof(float), stream);
    bn_stats_kernel<<<256, 128, 0, stream>>>(H1, stats, N);
    bn_apply_kernel<<<(N * D_IN + 255) / 256, 256, 0, stream>>>(H1, stats, g0, be0, N);

    // ---- layer 1 ----
    gemm_kernel<128><<<gb, 256, 0, stream>>>(H1, Wl1, Y, N);
    gemm_kernel<128><<<gb, 256, 0, stream>>>(H1, Wr1, H2, N);
    agg_kernel<128><<<N, 128, 0, stream>>>(Y, offs, sorted, b1, H2);
    hipMemsetAsync(stats, 0, 256 * sizeof(float), stream);
    bn_stats_kernel<<<256, 128, 0, stream>>>(H2, stats, N);
    bn_apply_kernel<<<(N * D_IN + 255) / 256, 256, 0, stream>>>(H2, stats, g1, be1, N);

    // ---- layer 2: out = log_softmax(mean(h@Wl2) + h@Wr2 + b2) ----
    gemm_kernel<64><<<gb, 256, 0, stream>>>(H2, Wl2, Y, N);
    gemm_kernel<64><<<gb, 256, 0, stream>>>(H2, Wr2, H1, N);
    agg_kernel<64><<<N, 64, 0, stream>>>(Y, offs, sorted, b2, H1);
    lsm_kernel<<<(N + 3) / 4, 256, 0, stream>>>(H1, (float*)d_out, N);
}

// Round 2
// 733.389 us; speedup vs baseline: 1.0323x; 1.0323x over previous
//
#include <hip/hip_runtime.h>
#include <hip/hip_bf16.h>

#define D_IN 128
#define D_OUT 64
#define BN_EPS 1e-5f

// ---------------- CSR construction ----------------

__global__ void hist_kernel(const int* __restrict__ dst, int* __restrict__ cnt, int E) {
    int i = blockIdx.x * blockDim.x + threadIdx.x;
    if (i < E) atomicAdd(&cnt[dst[i]], 1);
}

// single-block exclusive scan of cnt[0..n) -> offs[0..n]
__global__ void scan_kernel(const int* __restrict__ cnt, int* __restrict__ offs, int n) {
    __shared__ int wsum[16];
    __shared__ int carry_s;
    int tid = threadIdx.x;
    int lane = tid & 63, wid = tid >> 6;
    if (tid == 0) carry_s = 0;
    __syncthreads();
    const int CH = 4096; // 1024 threads * 4 elems
    for (int base = 0; base < n; base += CH) {
        int i0 = base + tid * 4;
        int v[4];
#pragma unroll
        for (int j = 0; j < 4; j++) { int i = i0 + j; v[j] = (i < n) ? cnt[i] : 0; }
        int tsum = v[0] + v[1] + v[2] + v[3];
        int sc = tsum;
#pragma unroll
        for (int off = 1; off < 64; off <<= 1) {
            int t = __shfl_up(sc, off);
            if (lane >= off) sc += t;
        }
        if (lane == 63) wsum[wid] = sc;
        __syncthreads();
        int wbase = 0;
        for (int w = 0; w < 16; w++) if (w < wid) wbase += wsum[w];
        int carry = carry_s;
        __syncthreads();
        int run = carry + wbase + sc - tsum; // exclusive prefix for first elem
#pragma unroll
        for (int j = 0; j < 4; j++) {
            int i = i0 + j;
            if (i < n) offs[i] = run;
            run += v[j];
        }
        if (tid == 1023) carry_s = carry + wbase + sc;
        __syncthreads();
    }
    if (tid == 0) offs[n] = carry_s;
}

__global__ void scatter_kernel(const int* __restrict__ src, const int* __restrict__ dst,
                               int* __restrict__ cursor, int* __restrict__ sorted_src, int E) {
    int i = blockIdx.x * blockDim.x + threadIdx.x;
    if (i < E) {
        int p = atomicAdd(&cursor[dst[i]], 1);
        sorted_src[p] = src[i];
    }
}

// ---------------- GEMM: C[M][TN] = A[M][128] @ W[128][TN] ----------------
// 128xTN block tile, BK=32, 256 threads, 8x(TN/16) per-thread micro-tile.
// As stride 33 -> A reads are 4-address broadcasts, conflict-free.

template <int TN>
__global__ __launch_bounds__(256) void gemm_kernel(const float* __restrict__ A,
                                                   const float* __restrict__ W,
                                                   float* __restrict__ C, int M) {
    const int BM = 128, BK = 32;
    const int TC = TN / 16;           // 8 or 4 cols per thread
    const int ASTR = 33;              // padded stride (words)
    __shared__ float As[BM * ASTR];   // 128*33*4 = 16.9 KB
    __shared__ float Bs[BK * TN];     // 16 KB (TN=128) / 8 KB (TN=64)

    int tid = threadIdx.x;
    int row0 = blockIdx.x * BM;
    int tc = tid & 15;   // col group
    int tr = tid >> 4;   // row group (wave: tr 0..3)

    float acc[8][TC];
#pragma unroll
    for (int i = 0; i < 8; i++)
#pragma unroll
        for (int j = 0; j < TC; j++) acc[i][j] = 0.f;

    for (int k0 = 0; k0 < D_IN; k0 += BK) {
        // stage A: 128 rows x 32 cols, 1024 float4 chunks / 256 threads
#pragma unroll
        for (int it = 0; it < 4; it++) {
            int l = tid + it * 256;
            int r = l >> 3;             // 0..127
            int c4 = (l & 7) << 2;      // 0,4,..,28
            int gr = row0 + r;
            float4 v = make_float4(0.f, 0.f, 0.f, 0.f);
            if (gr < M) v = *(const float4*)&A[(size_t)gr * D_IN + k0 + c4];
            float* p = &As[r * ASTR + c4];
            p[0] = v.x; p[1] = v.y; p[2] = v.z; p[3] = v.w;
        }
        // stage B: 32 x TN
#pragma unroll
        for (int it = 0; it < BK * TN / 4 / 256; it++) {
            int l = tid + it * 256;
            int r = l / (TN / 4);
            int c4 = (l % (TN / 4)) << 2;
            *(float4*)&Bs[r * TN + c4] = *(const float4*)&W[(size_t)(k0 + r) * TN + c4];
        }
        __syncthreads();
#pragma unroll
        for (int k = 0; k < BK; k++) {
            float a[8];
#pragma unroll
            for (int i = 0; i < 8; i++) a[i] = As[(tr * 8 + i) * ASTR + k];
            float b[TC];
#pragma unroll
            for (int j = 0; j < TC; j += 4) {
                float4 bv = *(const float4*)&Bs[k * TN + tc * TC + j];
                b[j] = bv.x; b[j + 1] = bv.y; b[j + 2] = bv.z; b[j + 3] = bv.w;
            }
#pragma unroll
            for (int i = 0; i < 8; i++)
#pragma unroll
                for (int j = 0; j < TC; j++) acc[i][j] += a[i] * b[j];
        }
        __syncthreads();
    }
#pragma unroll
    for (int i = 0; i < 8; i++) {
        int gr = row0 + tr * 8 + i;
        if (gr < M) {
#pragma unroll
            for (int j = 0; j < TC; j += 4) {
                *(float4*)&C[(size_t)gr * TN + tc * TC + j] =
                    make_float4(acc[i][j], acc[i][j + 1], acc[i][j + 2], acc[i][j + 3]);
            }
        }
    }
}

// ---------------- aggregation: H[node] += mean_neighbors(Y) + bias ----------------

template <int D>
__global__ void agg_kernel(const float* __restrict__ Y, const int* __restrict__ offs,
                           const int* __restrict__ sorted_src, const float* __restrict__ bias,
                           float* __restrict__ H) {
    int node = blockIdx.x;
    int t = threadIdx.x; // D threads
    int s0 = offs[node], s1 = offs[node + 1];
    float acc = 0.f;
    int k = s0;
    for (; k + 4 <= s1; k += 4) {
        int i0 = sorted_src[k];
        int i1 = sorted_src[k + 1];
        int i2 = sorted_src[k + 2];
        int i3 = sorted_src[k + 3];
        float v0 = Y[(size_t)i0 * D + t];
        float v1 = Y[(size_t)i1 * D + t];
        float v2 = Y[(size_t)i2 * D + t];
        float v3 = Y[(size_t)i3 * D + t];
        acc += v0 + v1 + v2 + v3;
    }
    for (; k < s1; k++) acc += Y[(size_t)sorted_src[k] * D + t];
    float inv = 1.0f / fmaxf((float)(s1 - s0), 1.0f);
    H[(size_t)node * D + t] += acc * inv + bias[t];
}

// ---------------- BatchNorm ----------------

__global__ void bn_stats_kernel(const float* __restrict__ H, float* __restrict__ stats, int M) {
    int col = threadIdx.x; // 128
    float s = 0.f, s2 = 0.f;
    for (int r = blockIdx.x; r < M; r += gridDim.x) {
        float v = H[(size_t)r * D_IN + col];
        s += v;
        s2 += v * v;
    }
    atomicAdd(&stats[col], s);
    atomicAdd(&stats[D_IN + col], s2);
}

__global__ void bn_apply_kernel(float* __restrict__ H, const float* __restrict__ stats,
                                const float* __restrict__ gamma, const float* __restrict__ beta,
                                int M) {
    int idx = blockIdx.x * blockDim.x + threadIdx.x;
    if (idx >= M * D_IN) return;
    int col = idx & (D_IN - 1);
    float invM = 1.0f / (float)M;
    float mu = stats[col] * invM;
    float var = stats[D_IN + col] * invM - mu * mu;
    float v = (H[idx] - mu) * rsqrtf(var + BN_EPS) * gamma[col] + beta[col];
    H[idx] = fmaxf(v, 0.f);
}

// ---------------- log_softmax over rows of 64 ----------------

__global__ void lsm_kernel(const float* __restrict__ H, float* __restrict__ out, int M) {
    int node = blockIdx.x * (blockDim.x / 64) + (threadIdx.x >> 6);
    int lane = threadIdx.x & 63;
    if (node >= M) return;
    float v = H[(size_t)node * D_OUT + lane];
    float m = v;
#pragma unroll
    for (int off = 32; off; off >>= 1) m = fmaxf(m, __shfl_xor(m, off));
    float e = expf(v - m);
    float s = e;
#pragma unroll
    for (int off = 32; off; off >>= 1) s += __shfl_xor(s, off);
    out[(size_t)node * D_OUT + lane] = (v - m) - logf(s);
}

// ---------------- launch ----------------

extern "C" void kernel_launch(void* const* d_in, const int* in_sizes, int n_in,
                              void* d_out, int out_size, void* d_ws, size_t ws_size,
                              hipStream_t stream) {
    const float* x   = (const float*)d_in[0];
    const int*   ei  = (const int*)d_in[1];
    const float* Wl0 = (const float*)d_in[2];
    const float* Wr0 = (const float*)d_in[3];
    const float* b0  = (const float*)d_in[4];
    const float* g0  = (const float*)d_in[5];
    const float* be0 = (const float*)d_in[6];
    const float* Wl1 = (const float*)d_in[7];
    const float* Wr1 = (const float*)d_in[8];
    const float* b1  = (const float*)d_in[9];
    const float* g1  = (const float*)d_in[10];
    const float* be1 = (const float*)d_in[11];
    const float* Wl2 = (const float*)d_in[12];
    const float* Wr2 = (const float*)d_in[13];
    const float* b2  = (const float*)d_in[14];

    const int N = in_sizes[0] / D_IN;   // 50000
    const int E = in_sizes[1] / 2;      // 800000

    float* Y  = (float*)d_ws;
    float* H1 = Y + (size_t)N * D_IN;
    float* H2 = H1 + (size_t)N * D_IN;
    int* cnt    = (int*)(H2 + (size_t)N * D_IN);
    int* offs   = cnt + N;
    int* cursor = offs + N + 1;
    int* sorted = cursor + N;
    float* stats = (float*)(sorted + E);

    // ---- CSR build (once, reused by all 3 layers) ----
    hipMemsetAsync(cnt, 0, (size_t)N * sizeof(int), stream);
    hist_kernel<<<(E + 255) / 256, 256, 0, stream>>>(ei + E, cnt, E);
    scan_kernel<<<1, 1024, 0, stream>>>(cnt, offs, N);
    hipMemcpyAsync(cursor, offs, (size_t)N * sizeof(int), hipMemcpyDeviceToDevice, stream);
    scatter_kernel<<<(E + 255) / 256, 256, 0, stream>>>(ei, ei + E, cursor, sorted, E);

    const int gb = (N + 127) / 128;

    // ---- layer 0: h = mean(x@Wl0) + x@Wr0 + b0 ; BN+ReLU ----
    gemm_kernel<128><<<gb, 256, 0, stream>>>(x, Wl0, Y, N);
    gemm_kernel<128><<<gb, 256, 0, stream>>>(x, Wr0, H1, N);
    agg_kernel<128><<<N, 128, 0, stream>>>(Y, offs, sorted, b0, H1);
    hipMemsetAsync(stats, 0, 256 * sizeof(float), stream);
    bn_stats_kernel<<<256, 128, 0, stream>>>(H1, stats, N);
    bn_apply_kernel<<<(N * D_IN + 255) / 256, 256, 0, stream>>>(H1, stats, g0, be0, N);

    // ---- layer 1 ----
    gemm_kernel<128><<<gb, 256, 0, stream>>>(H1, Wl1, Y, N);
    gemm_kernel<128><<<gb, 256, 0, stream>>>(H1, Wr1, H2, N);
    agg_kernel<128><<<N, 128, 0, stream>>>(Y, offs, sorted, b1, H2);
    hipMemsetAsync(stats, 0, 256 * sizeof(float), stream);
    bn_stats_kernel<<<256, 128, 0, stream>>>(H2, stats, N);
    bn_apply_kernel<<<(N * D_IN + 255) / 256, 256, 0, stream>>>(H2, stats, g1, be1, N);

    // ---- layer 2: out = log_softmax(mean(h@Wl2) + h@Wr2 + b2) ----
    gemm_kernel<64><<<gb, 256, 0, stream>>>(H2, Wl2, Y, N);
    gemm_kernel<64><<<gb, 256, 0, stream>>>(H2, Wr2, H1, N);
    agg_kernel<64><<<N, 64, 0, stream>>>(Y, offs, sorted, b2, H1);
    lsm_kernel<<<(N + 3) / 4, 256, 0, stream>>>(H1, (float*)d_out, N);
}

// Round 3
// 567.322 us; speedup vs baseline: 1.3344x; 1.2927x over previous
//
#include <hip/hip_runtime.h>
#include <hip/hip_bf16.h>

#define D_IN 128
#define D_OUT 64
#define BN_EPS 1e-5f

typedef short short8 __attribute__((ext_vector_type(8)));
typedef float f32x4 __attribute__((ext_vector_type(4)));

// ---------------- CSR construction ----------------

__global__ void hist_kernel(const int* __restrict__ dst, int* __restrict__ cnt, int E) {
    int i = blockIdx.x * blockDim.x + threadIdx.x;
    if (i < E) atomicAdd(&cnt[dst[i]], 1);
}

__global__ void scan_kernel(const int* __restrict__ cnt, int* __restrict__ offs, int n) {
    __shared__ int wsum[16];
    __shared__ int carry_s;
    int tid = threadIdx.x;
    int lane = tid & 63, wid = tid >> 6;
    if (tid == 0) carry_s = 0;
    __syncthreads();
    const int CH = 4096;
    for (int base = 0; base < n; base += CH) {
        int i0 = base + tid * 4;
        int v[4];
#pragma unroll
        for (int j = 0; j < 4; j++) { int i = i0 + j; v[j] = (i < n) ? cnt[i] : 0; }
        int tsum = v[0] + v[1] + v[2] + v[3];
        int sc = tsum;
#pragma unroll
        for (int off = 1; off < 64; off <<= 1) {
            int t = __shfl_up(sc, off);
            if (lane >= off) sc += t;
        }
        if (lane == 63) wsum[wid] = sc;
        __syncthreads();
        int wbase = 0;
        for (int w = 0; w < 16; w++) if (w < wid) wbase += wsum[w];
        int carry = carry_s;
        __syncthreads();
        int run = carry + wbase + sc - tsum;
#pragma unroll
        for (int j = 0; j < 4; j++) {
            int i = i0 + j;
            if (i < n) offs[i] = run;
            run += v[j];
        }
        if (tid == 1023) carry_s = carry + wbase + sc;
        __syncthreads();
    }
    if (tid == 0) offs[n] = carry_s;
}

__global__ void scatter_kernel(const int* __restrict__ src, const int* __restrict__ dst,
                               int* __restrict__ cursor, int* __restrict__ sorted_src, int E) {
    int i = blockIdx.x * blockDim.x + threadIdx.x;
    if (i < E) {
        int p = atomicAdd(&cursor[dst[i]], 1);
        sorted_src[p] = src[i];
    }
}

// ---------------- weight swizzle: W[K][Nn] f32 -> B-fragment-ordered bf16 ----------------
// chunk (nf, kk): 64 lanes x 8 bf16; lane l elem j = W[kk*32 + (l>>4)*8 + j][nf*16 + (l&15)]

__global__ void wswz_kernel(const float* __restrict__ Wl, const float* __restrict__ Wr,
                            short* __restrict__ outL, short* __restrict__ outR, int Nn) {
    const float* W = blockIdx.y ? Wr : Wl;
    short* out = blockIdx.y ? outR : outL;
    int g = blockIdx.x * 256 + threadIdx.x;
    int nchunks = (Nn / 16) * 4;
    int chunk = g >> 6, lane = g & 63;
    if (chunk >= nchunks) return;
    int nf = chunk >> 2, kk = chunk & 3;
    short8 s = {0, 0, 0, 0, 0, 0, 0, 0};
#pragma unroll
    for (int j = 0; j < 8; j++) {
        float v = W[(size_t)(kk * 32 + (lane >> 4) * 8 + j) * Nn + nf * 16 + (lane & 15)];
        union { __hip_bfloat16 h; short s; } cv;
        cv.h = __float2bfloat16(v);
        s[j] = cv.s;
    }
    *(short8*)&out[((size_t)(chunk << 6) + lane) * 8] = s;
}

// ---------------- x -> bf16 ----------------

__global__ void cvt_x_kernel(const float* __restrict__ x, __hip_bfloat16* __restrict__ xb, int n4) {
    int g = blockIdx.x * 256 + threadIdx.x;
    if (g >= n4) return;
    float4 v = ((const float4*)x)[g];
    union { __hip_bfloat16 h[4]; uint2 u; } o;
    o.h[0] = __float2bfloat16(v.x);
    o.h[1] = __float2bfloat16(v.y);
    o.h[2] = __float2bfloat16(v.z);
    o.h[3] = __float2bfloat16(v.w);
    ((uint2*)xb)[g] = o.u;
}

// ---------------- fused dual MFMA GEMM: Y = A@Wl, Z = A@Wr ----------------
// A bf16 [M][128]; W pre-swizzled fragment layout; BM=64 rows/block.
// TN=128: 4 waves (2 for Y cols 0/64, 2 for Z); TN=64: 2 waves (Y, Z).

template <int TN>
__global__ __launch_bounds__(TN == 128 ? 256 : 128)
void gemm2_mfma(const __hip_bfloat16* __restrict__ A, const short* __restrict__ WlF,
                const short* __restrict__ WrF, float* __restrict__ Y, float* __restrict__ Z,
                int M) {
    __shared__ short As[64 * 136];  // pitch 136 bf16 = 272B -> 2-way-free b128 reads
    const int tid = threadIdx.x;
    const int lane = tid & 63;
    const int w = tid >> 6;
    const int row0 = blockIdx.x * 64;
    const int NT = (TN == 128) ? 256 : 128;
    const short* Ag = (const short*)A;

    for (int c = tid; c < 1024; c += NT) {
        int r = c >> 4, off = (c & 15) * 8;
        short8 v = {0, 0, 0, 0, 0, 0, 0, 0};
        if (row0 + r < M) v = *(const short8*)&Ag[(size_t)(row0 + r) * 128 + off];
        *(short8*)&As[r * 136 + off] = v;
    }
    __syncthreads();

    const short* WF;
    float* P;
    int col0;
    if (TN == 128) {
        WF = (w < 2) ? WlF : WrF;
        P = (w < 2) ? Y : Z;
        col0 = (w & 1) * 64;
    } else {
        WF = w ? WrF : WlF;
        P = w ? Z : Y;
        col0 = 0;
    }

    // A fragments: lane l -> A[m*16 + (l&15)][kk*32 + (l>>4)*8 .. +8]
    short8 a[4][4];
#pragma unroll
    for (int m = 0; m < 4; m++)
#pragma unroll
        for (int kk = 0; kk < 4; kk++)
            a[m][kk] = *(const short8*)&As[(m * 16 + (lane & 15)) * 136 + kk * 32 + (lane >> 4) * 8];

    f32x4 acc[4][4];
#pragma unroll
    for (int m = 0; m < 4; m++)
#pragma unroll
        for (int n = 0; n < 4; n++) acc[m][n] = (f32x4){0.f, 0.f, 0.f, 0.f};

#pragma unroll
    for (int kk = 0; kk < 4; kk++) {
#pragma unroll
        for (int n = 0; n < 4; n++) {
            short8 b = *(const short8*)&WF[(size_t)(((col0 >> 4) + n) * 4 + kk) * 512 + lane * 8];
#pragma unroll
            for (int m = 0; m < 4; m++)
                acc[m][n] = __builtin_amdgcn_mfma_f32_16x16x32_bf16(a[m][kk], b, acc[m][n], 0, 0, 0);
        }
    }

    // C/D: col = lane&15, row = (lane>>4)*4 + reg
#pragma unroll
    for (int m = 0; m < 4; m++) {
#pragma unroll
        for (int i = 0; i < 4; i++) {
            int gr = row0 + m * 16 + (lane >> 4) * 4 + i;
            if (gr < M) {
#pragma unroll
                for (int n = 0; n < 4; n++)
                    P[(size_t)gr * TN + col0 + n * 16 + (lane & 15)] = acc[m][n][i];
            }
        }
    }
}

// ---------------- aggregation: H[node] += mean_neighbors(Y) + bias ----------------

template <int D>
__global__ void agg_kernel(const float* __restrict__ Y, const int* __restrict__ offs,
                           const int* __restrict__ sorted_src, const float* __restrict__ bias,
                           float* __restrict__ H) {
    int node = blockIdx.x;
    int t = threadIdx.x;
    int s0 = offs[node], s1 = offs[node + 1];
    float acc = 0.f;
    int k = s0;
    for (; k + 4 <= s1; k += 4) {
        int i0 = sorted_src[k];
        int i1 = sorted_src[k + 1];
        int i2 = sorted_src[k + 2];
        int i3 = sorted_src[k + 3];
        float v0 = Y[(size_t)i0 * D + t];
        float v1 = Y[(size_t)i1 * D + t];
        float v2 = Y[(size_t)i2 * D + t];
        float v3 = Y[(size_t)i3 * D + t];
        acc += v0 + v1 + v2 + v3;
    }
    for (; k < s1; k++) acc += Y[(size_t)sorted_src[k] * D + t];
    float inv = 1.0f / fmaxf((float)(s1 - s0), 1.0f);
    H[(size_t)node * D + t] += acc * inv + bias[t];
}

// ---------------- BatchNorm ----------------

__global__ void bn_stats_kernel(const float* __restrict__ H, float* __restrict__ stats, int M) {
    int col = threadIdx.x;
    float s = 0.f, s2 = 0.f;
    for (int r = blockIdx.x; r < M; r += gridDim.x) {
        float v = H[(size_t)r * D_IN + col];
        s += v;
        s2 += v * v;
    }
    atomicAdd(&stats[col], s);
    atomicAdd(&stats[D_IN + col], s2);
}

// normalize + ReLU, emit bf16 (next layer's GEMM input)
__global__ void bn_apply_kernel(const float* __restrict__ H, __hip_bfloat16* __restrict__ Hb,
                                const float* __restrict__ stats, const float* __restrict__ gamma,
                                const float* __restrict__ beta, int M) {
    int idx = blockIdx.x * blockDim.x + threadIdx.x;
    if (idx >= M * D_IN) return;
    int col = idx & (D_IN - 1);
    float invM = 1.0f / (float)M;
    float mu = stats[col] * invM;
    float var = stats[D_IN + col] * invM - mu * mu;
    float v = (H[idx] - mu) * rsqrtf(var + BN_EPS) * gamma[col] + beta[col];
    Hb[idx] = __float2bfloat16(fmaxf(v, 0.f));
}

// ---------------- log_softmax over rows of 64 ----------------

__global__ void lsm_kernel(const float* __restrict__ H, float* __restrict__ out, int M) {
    int node = blockIdx.x * (blockDim.x / 64) + (threadIdx.x >> 6);
    int lane = threadIdx.x & 63;
    if (node >= M) return;
    float v = H[(size_t)node * D_OUT + lane];
    float m = v;
#pragma unroll
    for (int off = 32; off; off >>= 1) m = fmaxf(m, __shfl_xor(m, off));
    float e = expf(v - m);
    float s = e;
#pragma unroll
    for (int off = 32; off; off >>= 1) s += __shfl_xor(s, off);
    out[(size_t)node * D_OUT + lane] = (v - m) - logf(s);
}

// ---------------- launch ----------------

extern "C" void kernel_launch(void* const* d_in, const int* in_sizes, int n_in,
                              void* d_out, int out_size, void* d_ws, size_t ws_size,
                              hipStream_t stream) {
    const float* x   = (const float*)d_in[0];
    const int*   ei  = (const int*)d_in[1];
    const float* Wl0 = (const float*)d_in[2];
    const float* Wr0 = (const float*)d_in[3];
    const float* b0  = (const float*)d_in[4];
    const float* g0  = (const float*)d_in[5];
    const float* be0 = (const float*)d_in[6];
    const float* Wl1 = (const float*)d_in[7];
    const float* Wr1 = (const float*)d_in[8];
    const float* b1  = (const float*)d_in[9];
    const float* g1  = (const float*)d_in[10];
    const float* be1 = (const float*)d_in[11];
    const float* Wl2 = (const float*)d_in[12];
    const float* Wr2 = (const float*)d_in[13];
    const float* b2  = (const float*)d_in[14];

    const int N = in_sizes[0] / D_IN;   // 50000
    const int E = in_sizes[1] / 2;      // 800000

    // workspace layout
    float* Y = (float*)d_ws;                       // N*128 f32
    float* H = Y + (size_t)N * D_IN;               // N*128 f32
    __hip_bfloat16* Hb = (__hip_bfloat16*)(H + (size_t)N * D_IN);  // N*128 bf16 (also xb)
    int* cnt    = (int*)(Hb + (size_t)N * D_IN);
    int* offs   = cnt + N;
    int* cursor = offs + N + 1;
    int* sorted = cursor + N;
    float* stats = (float*)(sorted + E);
    short* WlF0 = (short*)(stats + 256);
    short* WrF0 = WlF0 + 16384;
    short* WlF1 = WrF0 + 16384;
    short* WrF1 = WlF1 + 16384;
    short* WlF2 = WrF1 + 16384;
    short* WrF2 = WlF2 + 8192;

    // ---- CSR build ----
    hipMemsetAsync(cnt, 0, (size_t)N * sizeof(int), stream);
    hist_kernel<<<(E + 255) / 256, 256, 0, stream>>>(ei + E, cnt, E);
    scan_kernel<<<1, 1024, 0, stream>>>(cnt, offs, N);
    hipMemcpyAsync(cursor, offs, (size_t)N * sizeof(int), hipMemcpyDeviceToDevice, stream);
    scatter_kernel<<<(E + 255) / 256, 256, 0, stream>>>(ei, ei + E, cursor, sorted, E);

    // ---- weight swizzle + x->bf16 ----
    wswz_kernel<<<dim3(8, 2), 256, 0, stream>>>(Wl0, Wr0, WlF0, WrF0, 128);
    wswz_kernel<<<dim3(8, 2), 256, 0, stream>>>(Wl1, Wr1, WlF1, WrF1, 128);
    wswz_kernel<<<dim3(4, 2), 256, 0, stream>>>(Wl2, Wr2, WlF2, WrF2, 64);
    cvt_x_kernel<<<(N * D_IN / 4 + 255) / 256, 256, 0, stream>>>(x, Hb, N * D_IN / 4);

    const int gb = (N + 63) / 64;  // 782

    // ---- layer 0 ----
    gemm2_mfma<128><<<gb, 256, 0, stream>>>(Hb, WlF0, WrF0, Y, H, N);
    agg_kernel<128><<<N, 128, 0, stream>>>(Y, offs, sorted, b0, H);
    hipMemsetAsync(stats, 0, 256 * sizeof(float), stream);
    bn_stats_kernel<<<256, 128, 0, stream>>>(H, stats, N);
    bn_apply_kernel<<<(N * D_IN + 255) / 256, 256, 0, stream>>>(H, Hb, stats, g0, be0, N);

    // ---- layer 1 ----
    gemm2_mfma<128><<<gb, 256, 0, stream>>>(Hb, WlF1, WrF1, Y, H, N);
    agg_kernel<128><<<N, 128, 0, stream>>>(Y, offs, sorted, b1, H);
    hipMemsetAsync(stats, 0, 256 * sizeof(float), stream);
    bn_stats_kernel<<<256, 128, 0, stream>>>(H, stats, N);
    bn_apply_kernel<<<(N * D_IN + 255) / 256, 256, 0, stream>>>(H, Hb, stats, g1, be1, N);

    // ---- layer 2 ----
    gemm2_mfma<64><<<gb, 128, 0, stream>>>(Hb, WlF2, WrF2, Y, H, N);
    agg_kernel<64><<<N, 64, 0, stream>>>(Y, offs, sorted, b2, H);
    lsm_kernel<<<(N + 3) / 4, 256, 0, stream>>>(H, (float*)d_out, N);
}

// Round 4
// 519.896 us; speedup vs baseline: 1.4562x; 1.0912x over previous
//
#include <hip/hip_runtime.h>
#include <hip/hip_bf16.h>

#define D_IN 128
#define D_OUT 64
#define BN_EPS 1e-5f

typedef short short8 __attribute__((ext_vector_type(8)));
typedef float f32x4 __attribute__((ext_vector_type(4)));
typedef unsigned short ushort_t;
typedef unsigned int uint_t;

__device__ __forceinline__ float bf16lo(uint_t v) { return __uint_as_float(v << 16); }
__device__ __forceinline__ float bf16hi(uint_t v) { return __uint_as_float(v & 0xffff0000u); }
__device__ __forceinline__ ushort_t f2bf(float f) {
    union { __hip_bfloat16 h; ushort_t u; } cv;
    cv.h = __float2bfloat16(f);
    return cv.u;
}

// ---------------- CSR construction (dst-range tiled: blockIdx.y = pass) ----------------

__global__ void hist_kernel(const int* __restrict__ dst, int* __restrict__ cnt, int E, int passW) {
    int lo = blockIdx.y * passW, hi = lo + passW;
    int i = blockIdx.x * 256 + threadIdx.x;
    if (i < E) {
        int d = dst[i];
        if (d >= lo && d < hi) atomicAdd(&cnt[d], 1);
    }
}

__global__ void scan_kernel(const int* __restrict__ cnt, int* __restrict__ offs, int n) {
    __shared__ int wsum[16];
    __shared__ int carry_s;
    int tid = threadIdx.x;
    int lane = tid & 63, wid = tid >> 6;
    if (tid == 0) carry_s = 0;
    __syncthreads();
    const int CH = 4096;
    for (int base = 0; base < n; base += CH) {
        int i0 = base + tid * 4;
        int v[4];
#pragma unroll
        for (int j = 0; j < 4; j++) { int i = i0 + j; v[j] = (i < n) ? cnt[i] : 0; }
        int tsum = v[0] + v[1] + v[2] + v[3];
        int sc = tsum;
#pragma unroll
        for (int off = 1; off < 64; off <<= 1) {
            int t = __shfl_up(sc, off);
            if (lane >= off) sc += t;
        }
        if (lane == 63) wsum[wid] = sc;
        __syncthreads();
        int wbase = 0;
        for (int w = 0; w < 16; w++) if (w < wid) wbase += wsum[w];
        int carry = carry_s;
        __syncthreads();
        int run = carry + wbase + sc - tsum;
#pragma unroll
        for (int j = 0; j < 4; j++) {
            int i = i0 + j;
            if (i < n) offs[i] = run;
            run += v[j];
        }
        if (tid == 1023) carry_s = carry + wbase + sc;
        __syncthreads();
    }
    if (tid == 0) offs[n] = carry_s;
}

__global__ void scatter_kernel(const int* __restrict__ src, const int* __restrict__ dst,
                               int* __restrict__ cursor, ushort_t* __restrict__ sorted_src,
                               int E, int passW) {
    int lo = blockIdx.y * passW, hi = lo + passW;
    int i = blockIdx.x * 256 + threadIdx.x;
    if (i < E) {
        int d = dst[i];
        int s = src[i];
        if (d >= lo && d < hi) {
            int p = atomicAdd(&cursor[d], 1);
            sorted_src[p] = (ushort_t)s;
        }
    }
}

// ---------------- weight swizzle (all 3 layers in one launch) ----------------
// chunk (nf, kk): 64 lanes x 8 bf16; lane l elem j = W[kk*32 + (l>>4)*8 + j][nf*16 + (l&15)]

__global__ void wswz_kernel(const float* __restrict__ Wl0, const float* __restrict__ Wr0,
                            const float* __restrict__ Wl1, const float* __restrict__ Wr1,
                            const float* __restrict__ Wl2, const float* __restrict__ Wr2,
                            short* __restrict__ o0l, short* __restrict__ o0r,
                            short* __restrict__ o1l, short* __restrict__ o1r,
                            short* __restrict__ o2l, short* __restrict__ o2r) {
    int layer = blockIdx.z;
    int Nn = (layer == 2) ? 64 : 128;
    const float* W;
    short* out;
    if (layer == 0) { W = blockIdx.y ? Wr0 : Wl0; out = blockIdx.y ? o0r : o0l; }
    else if (layer == 1) { W = blockIdx.y ? Wr1 : Wl1; out = blockIdx.y ? o1r : o1l; }
    else { W = blockIdx.y ? Wr2 : Wl2; out = blockIdx.y ? o2r : o2l; }
    int g = blockIdx.x * 256 + threadIdx.x;
    int nchunks = (Nn / 16) * 4;
    int chunk = g >> 6, lane = g & 63;
    if (chunk >= nchunks) return;
    int nf = chunk >> 2, kk = chunk & 3;
    short8 s;
#pragma unroll
    for (int j = 0; j < 8; j++) {
        float v = W[(size_t)(kk * 32 + (lane >> 4) * 8 + j) * Nn + nf * 16 + (lane & 15)];
        s[j] = (short)f2bf(v);
    }
    *(short8*)&out[((size_t)(chunk << 6) + lane) * 8] = s;
}

// ---------------- x -> bf16 (+ zero BN stats) ----------------

__global__ void cvt_x_kernel(const float* __restrict__ x, __hip_bfloat16* __restrict__ xb,
                             int n4, float* __restrict__ stats) {
    if (blockIdx.x == 0 && threadIdx.x < 512) stats[threadIdx.x] = 0.f;
    int g = blockIdx.x * 256 + threadIdx.x;
    if (g >= n4) return;
    float4 v = ((const float4*)x)[g];
    union { __hip_bfloat16 h[4]; uint2 u; } o;
    o.h[0] = __float2bfloat16(v.x);
    o.h[1] = __float2bfloat16(v.y);
    o.h[2] = __float2bfloat16(v.z);
    o.h[3] = __float2bfloat16(v.w);
    ((uint2*)xb)[g] = o.u;
}

// ---------------- fused dual MFMA GEMM: Yb(bf16) = A@Wl, Z(f32) = A@Wr ----------------

template <int TN>
__global__ __launch_bounds__(TN == 128 ? 256 : 128)
void gemm2_mfma(const __hip_bfloat16* __restrict__ A, const short* __restrict__ WlF,
                const short* __restrict__ WrF, ushort_t* __restrict__ Yb,
                float* __restrict__ Z, int M) {
    __shared__ short As[64 * 136];
    const int tid = threadIdx.x;
    const int lane = tid & 63;
    const int w = tid >> 6;
    const int row0 = blockIdx.x * 64;
    const int NT = (TN == 128) ? 256 : 128;
    const short* Ag = (const short*)A;

    for (int c = tid; c < 1024; c += NT) {
        int r = c >> 4, off = (c & 15) * 8;
        short8 v = {0, 0, 0, 0, 0, 0, 0, 0};
        if (row0 + r < M) v = *(const short8*)&Ag[(size_t)(row0 + r) * 128 + off];
        *(short8*)&As[r * 136 + off] = v;
    }
    __syncthreads();

    const short* WF;
    bool isY;
    int col0;
    if (TN == 128) {
        isY = (w < 2);
        WF = isY ? WlF : WrF;
        col0 = (w & 1) * 64;
    } else {
        isY = (w == 0);
        WF = isY ? WlF : WrF;
        col0 = 0;
    }

    short8 a[4][4];
#pragma unroll
    for (int m = 0; m < 4; m++)
#pragma unroll
        for (int kk = 0; kk < 4; kk++)
            a[m][kk] = *(const short8*)&As[(m * 16 + (lane & 15)) * 136 + kk * 32 + (lane >> 4) * 8];

    f32x4 acc[4][4];
#pragma unroll
    for (int m = 0; m < 4; m++)
#pragma unroll
        for (int n = 0; n < 4; n++) acc[m][n] = (f32x4){0.f, 0.f, 0.f, 0.f};

#pragma unroll
    for (int kk = 0; kk < 4; kk++) {
#pragma unroll
        for (int n = 0; n < 4; n++) {
            short8 b = *(const short8*)&WF[(size_t)(((col0 >> 4) + n) * 4 + kk) * 512 + lane * 8];
#pragma unroll
            for (int m = 0; m < 4; m++)
                acc[m][n] = __builtin_amdgcn_mfma_f32_16x16x32_bf16(a[m][kk], b, acc[m][n], 0, 0, 0);
        }
    }

    // C/D: col = lane&15, row = (lane>>4)*4 + reg
#pragma unroll
    for (int m = 0; m < 4; m++) {
#pragma unroll
        for (int i = 0; i < 4; i++) {
            int gr = row0 + m * 16 + (lane >> 4) * 4 + i;
            if (gr < M) {
                if (isY) {
#pragma unroll
                    for (int n = 0; n < 4; n++)
                        Yb[(size_t)gr * TN + col0 + n * 16 + (lane & 15)] = f2bf(acc[m][n][i]);
                } else {
#pragma unroll
                    for (int n = 0; n < 4; n++)
                        Z[(size_t)gr * TN + col0 + n * 16 + (lane & 15)] = acc[m][n][i];
                }
            }
        }
    }
}

// ---------------- aggregation (layers 0/1): H[node] += mean(Yb[srcs]) + bias ----------------
// one wave per node, lane handles 2 cols (uint = 2 bf16)

__global__ __launch_bounds__(256) void agg128_kernel(const ushort_t* __restrict__ Yb,
                                                     const int* __restrict__ offs,
                                                     const ushort_t* __restrict__ sorted_src,
                                                     const float* __restrict__ bias,
                                                     float* __restrict__ H, int N) {
    int node = blockIdx.x * 4 + (threadIdx.x >> 6);
    int lane = threadIdx.x & 63;
    if (node >= N) return;
    int s0 = offs[node], s1 = offs[node + 1];
    float a0 = 0.f, a1 = 0.f;
    int k = s0;
    for (; k + 4 <= s1; k += 4) {
        int i0 = sorted_src[k];
        int i1 = sorted_src[k + 1];
        int i2 = sorted_src[k + 2];
        int i3 = sorted_src[k + 3];
        uint_t v0 = *(const uint_t*)&Yb[(size_t)i0 * 128 + lane * 2];
        uint_t v1 = *(const uint_t*)&Yb[(size_t)i1 * 128 + lane * 2];
        uint_t v2 = *(const uint_t*)&Yb[(size_t)i2 * 128 + lane * 2];
        uint_t v3 = *(const uint_t*)&Yb[(size_t)i3 * 128 + lane * 2];
        a0 += bf16lo(v0) + bf16lo(v1) + bf16lo(v2) + bf16lo(v3);
        a1 += bf16hi(v0) + bf16hi(v1) + bf16hi(v2) + bf16hi(v3);
    }
    for (; k < s1; k++) {
        uint_t v = *(const uint_t*)&Yb[(size_t)sorted_src[k] * 128 + lane * 2];
        a0 += bf16lo(v);
        a1 += bf16hi(v);
    }
    float inv = 1.0f / fmaxf((float)(s1 - s0), 1.0f);
    float2 b = *(const float2*)&bias[lane * 2];
    float2* hp = (float2*)&H[(size_t)node * 128 + lane * 2];
    float2 h = *hp;
    h.x += a0 * inv + b.x;
    h.y += a1 * inv + b.y;
    *hp = h;
}

// ---------------- layer 2: agg + bias + log_softmax fused, writes d_out ----------------
// one wave per node; halves process alternating edges; lane&31 holds 2 cols

__global__ __launch_bounds__(256) void agg_lsm_kernel(const ushort_t* __restrict__ Yb,
                                                      const int* __restrict__ offs,
                                                      const ushort_t* __restrict__ sorted_src,
                                                      const float* __restrict__ bias,
                                                      const float* __restrict__ Z,
                                                      float* __restrict__ out, int N) {
    int node = blockIdx.x * 4 + (threadIdx.x >> 6);
    int lane = threadIdx.x & 63;
    int half = lane >> 5, l = lane & 31;
    if (node >= N) return;
    int s0 = offs[node], s1 = offs[node + 1];
    float a0 = 0.f, a1 = 0.f;
    for (int k = s0 + half; k < s1; k += 2) {
        uint_t v = *(const uint_t*)&Yb[(size_t)sorted_src[k] * 64 + l * 2];
        a0 += bf16lo(v);
        a1 += bf16hi(v);
    }
    a0 += __shfl_xor(a0, 32);
    a1 += __shfl_xor(a1, 32);
    float inv = 1.0f / fmaxf((float)(s1 - s0), 1.0f);
    float2 zb = *(const float2*)&Z[(size_t)node * 64 + l * 2];
    float2 bb = *(const float2*)&bias[l * 2];
    float v0 = zb.x + a0 * inv + bb.x;
    float v1 = zb.y + a1 * inv + bb.y;
    float m = fmaxf(v0, v1);
#pragma unroll
    for (int off = 16; off; off >>= 1) m = fmaxf(m, __shfl_xor(m, off));
    float s = expf(v0 - m) + expf(v1 - m);
#pragma unroll
    for (int off = 16; off; off >>= 1) s += __shfl_xor(s, off);
    float ls = logf(s);
    if (half == 0) {
        float2 o;
        o.x = v0 - m - ls;
        o.y = v1 - m - ls;
        *(float2*)&out[(size_t)node * 64 + l * 2] = o;
    }
}

// ---------------- BatchNorm ----------------

__global__ void bn_stats_kernel(const float* __restrict__ H, float* __restrict__ stats, int M) {
    int col = threadIdx.x;
    float s = 0.f, s2 = 0.f;
    for (int r = blockIdx.x; r < M; r += gridDim.x) {
        float v = H[(size_t)r * D_IN + col];
        s += v;
        s2 += v * v;
    }
    atomicAdd(&stats[col], s);
    atomicAdd(&stats[D_IN + col], s2);
}

__global__ void bn_apply_kernel(const float* __restrict__ H, __hip_bfloat16* __restrict__ Hb,
                                const float* __restrict__ stats, const float* __restrict__ gamma,
                                const float* __restrict__ beta, int M) {
    int idx = blockIdx.x * blockDim.x + threadIdx.x;
    if (idx >= M * D_IN) return;
    int col = idx & (D_IN - 1);
    float invM = 1.0f / (float)M;
    float mu = stats[col] * invM;
    float var = stats[D_IN + col] * invM - mu * mu;
    float v = (H[idx] - mu) * rsqrtf(var + BN_EPS) * gamma[col] + beta[col];
    Hb[idx] = __float2bfloat16(fmaxf(v, 0.f));
}

// ---------------- launch ----------------

extern "C" void kernel_launch(void* const* d_in, const int* in_sizes, int n_in,
                              void* d_out, int out_size, void* d_ws, size_t ws_size,
                              hipStream_t stream) {
    const float* x   = (const float*)d_in[0];
    const int*   ei  = (const int*)d_in[1];
    const float* Wl0 = (const float*)d_in[2];
    const float* Wr0 = (const float*)d_in[3];
    const float* b0  = (const float*)d_in[4];
    const float* g0  = (const float*)d_in[5];
    const float* be0 = (const float*)d_in[6];
    const float* Wl1 = (const float*)d_in[7];
    const float* Wr1 = (const float*)d_in[8];
    const float* b1  = (const float*)d_in[9];
    const float* g1  = (const float*)d_in[10];
    const float* be1 = (const float*)d_in[11];
    const float* Wl2 = (const float*)d_in[12];
    const float* Wr2 = (const float*)d_in[13];
    const float* b2  = (const float*)d_in[14];

    const int N = in_sizes[0] / D_IN;   // 50000
    const int E = in_sizes[1] / 2;      // 800000
    const int passW = (N + 7) / 8;      // 6250

    // workspace layout
    float* H = (float*)d_ws;                               // N*128 f32
    ushort_t* Yb = (ushort_t*)(H + (size_t)N * D_IN);      // N*128 bf16
    __hip_bfloat16* Hb = (__hip_bfloat16*)(Yb + (size_t)N * D_IN);  // N*128 bf16
    int* cnt    = (int*)(Hb + (size_t)N * D_IN);
    int* offs   = cnt + N;
    int* cursor = offs + N + 1;
    ushort_t* sorted = (ushort_t*)(cursor + N);            // E ushort
    float* stats = (float*)(sorted + E + (E & 1));         // 512 f32 (both layers)
    short* WlF0 = (short*)(stats + 512);
    short* WrF0 = WlF0 + 16384;
    short* WlF1 = WrF0 + 16384;
    short* WrF1 = WlF1 + 16384;
    short* WlF2 = WrF1 + 16384;
    short* WrF2 = WlF2 + 8192;

    const int eb = (E + 255) / 256;

    // ---- CSR build ----
    hipMemsetAsync(cnt, 0, (size_t)N * sizeof(int), stream);
    hist_kernel<<<dim3(eb, 8), 256, 0, stream>>>(ei + E, cnt, E, passW);
    scan_kernel<<<1, 1024, 0, stream>>>(cnt, offs, N);
    hipMemcpyAsync(cursor, offs, (size_t)N * sizeof(int), hipMemcpyDeviceToDevice, stream);
    scatter_kernel<<<dim3(eb, 8), 256, 0, stream>>>(ei, ei + E, cursor, sorted, E, passW);

    // ---- weight swizzle + x->bf16 (+stats zero) ----
    wswz_kernel<<<dim3(8, 2, 3), 256, 0, stream>>>(Wl0, Wr0, Wl1, Wr1, Wl2, Wr2,
                                                   WlF0, WrF0, WlF1, WrF1, WlF2, WrF2);
    cvt_x_kernel<<<(N * D_IN / 4 + 255) / 256, 256, 0, stream>>>(x, Hb, N * D_IN / 4, stats);

    const int gb = (N + 63) / 64;   // 782
    const int ab = (N + 3) / 4;     // 12500

    // ---- layer 0 ----
    gemm2_mfma<128><<<gb, 256, 0, stream>>>(Hb, WlF0, WrF0, Yb, H, N);
    agg128_kernel<<<ab, 256, 0, stream>>>(Yb, offs, sorted, b0, H, N);
    bn_stats_kernel<<<256, 128, 0, stream>>>(H, stats, N);
    bn_apply_kernel<<<(N * D_IN + 255) / 256, 256, 0, stream>>>(H, Hb, stats, g0, be0, N);

    // ---- layer 1 ----
    gemm2_mfma<128><<<gb, 256, 0, stream>>>(Hb, WlF1, WrF1, Yb, H, N);
    agg128_kernel<<<ab, 256, 0, stream>>>(Yb, offs, sorted, b1, H, N);
    bn_stats_kernel<<<256, 128, 0, stream>>>(H, stats + 256, N);
    bn_apply_kernel<<<(N * D_IN + 255) / 256, 256, 0, stream>>>(H, Hb, stats + 256, g1, be1, N);

    // ---- layer 2 (agg + bias + log_softmax fused) ----
    gemm2_mfma<64><<<gb, 128, 0, stream>>>(Hb, WlF2, WrF2, Yb, H, N);
    agg_lsm_kernel<<<ab, 256, 0, stream>>>(Yb, offs, sorted, b2, H, (float*)d_out, N);
}

// Round 5
// 415.463 us; speedup vs baseline: 1.8222x; 1.2514x over previous
//
#include <hip/hip_runtime.h>
#include <hip/hip_bf16.h>

#define D_IN 128
#define D_OUT 64
#define BN_EPS 1e-5f
#define NB_PART 512

typedef short short8 __attribute__((ext_vector_type(8)));
typedef float f32x4 __attribute__((ext_vector_type(4)));
typedef float f32x2 __attribute__((ext_vector_type(2)));
typedef unsigned short ushort_t;
typedef unsigned int uint_t;

__device__ __forceinline__ float bf16lo(uint_t v) { return __uint_as_float(v << 16); }
__device__ __forceinline__ float bf16hi(uint_t v) { return __uint_as_float(v & 0xffff0000u); }
__device__ __forceinline__ ushort_t f2bf(float f) {
    union { __hip_bfloat16 h; ushort_t u; } cv;
    cv.h = __float2bfloat16(f);
    return cv.u;
}
__device__ __forceinline__ f32x4 ntload4(const float* p) {
    return __builtin_nontemporal_load((const f32x4*)p);
}

// ---------------- CSR construction ----------------

__global__ void hist_kernel(const int* __restrict__ dst, int* __restrict__ cnt, int E) {
    int i = blockIdx.x * 256 + threadIdx.x;
    if (i < E) atomicAdd(&cnt[__builtin_nontemporal_load(&dst[i])], 1);
}

// hierarchical scan: part -> mid -> final
__global__ void scan_part_kernel(const int* __restrict__ cnt, int* __restrict__ bsum, int n) {
    int i = blockIdx.x * 256 + threadIdx.x;
    int v = (i < n) ? cnt[i] : 0;
#pragma unroll
    for (int off = 1; off < 64; off <<= 1) v += __shfl_xor(v, off);
    __shared__ int ws[4];
    int lane = threadIdx.x & 63, wid = threadIdx.x >> 6;
    if (lane == 0) ws[wid] = v;
    __syncthreads();
    if (threadIdx.x == 0) bsum[blockIdx.x] = ws[0] + ws[1] + ws[2] + ws[3];
}

__global__ void scan_mid_kernel(const int* __restrict__ bsum, int* __restrict__ bpre,
                                int* __restrict__ offs, int PB, int n) {
    int t = threadIdx.x;
    int v = (t < PB) ? bsum[t] : 0;
    int lane = t & 63, wid = t >> 6;
    int sc = v;
#pragma unroll
    for (int off = 1; off < 64; off <<= 1) {
        int u = __shfl_up(sc, off);
        if (lane >= off) sc += u;
    }
    __shared__ int ws[4];
    if (lane == 63) ws[wid] = sc;
    __syncthreads();
    int wb = 0;
    for (int w = 0; w < 4; w++) if (w < wid) wb += ws[w];
    int incl = sc + wb;
    if (t < PB) bpre[t] = incl - v;
    if (t == PB - 1) offs[n] = incl;
}

__global__ void scan_final_kernel(const int* __restrict__ cnt, const int* __restrict__ bpre,
                                  int* __restrict__ offs, int n) {
    int b = blockIdx.x, t = threadIdx.x;
    int i = b * 256 + t;
    int v = (i < n) ? cnt[i] : 0;
    int lane = t & 63, wid = t >> 6;
    int sc = v;
#pragma unroll
    for (int off = 1; off < 64; off <<= 1) {
        int u = __shfl_up(sc, off);
        if (lane >= off) sc += u;
    }
    __shared__ int ws[4];
    if (lane == 63) ws[wid] = sc;
    __syncthreads();
    int wb = 0;
    for (int w = 0; w < 4; w++) if (w < wid) wb += ws[w];
    if (i < n) offs[i] = bpre[b] + wb + sc - v;
}

__global__ void scatter_kernel(const int* __restrict__ src, const int* __restrict__ dst,
                               int* __restrict__ cursor, ushort_t* __restrict__ sorted_src,
                               int E, int passW) {
    int lo = blockIdx.y * passW, hi = lo + passW;
    int i = blockIdx.x * 256 + threadIdx.x;
    if (i < E) {
        int d = __builtin_nontemporal_load(&dst[i]);
        if (d >= lo && d < hi) {
            int s = __builtin_nontemporal_load(&src[i]);
            int p = atomicAdd(&cursor[d], 1);
            sorted_src[p] = (ushort_t)s;
        }
    }
}

// ---------------- weight swizzle (all 3 layers in one launch) ----------------
// chunk (nf, kk): 64 lanes x 8 bf16; lane l elem j = W[kk*32 + (l>>4)*8 + j][nf*16 + (l&15)]

__global__ void wswz_kernel(const float* __restrict__ Wl0, const float* __restrict__ Wr0,
                            const float* __restrict__ Wl1, const float* __restrict__ Wr1,
                            const float* __restrict__ Wl2, const float* __restrict__ Wr2,
                            short* __restrict__ o0l, short* __restrict__ o0r,
                            short* __restrict__ o1l, short* __restrict__ o1r,
                            short* __restrict__ o2l, short* __restrict__ o2r) {
    int layer = blockIdx.z;
    int Nn = (layer == 2) ? 64 : 128;
    const float* W;
    short* out;
    if (layer == 0) { W = blockIdx.y ? Wr0 : Wl0; out = blockIdx.y ? o0r : o0l; }
    else if (layer == 1) { W = blockIdx.y ? Wr1 : Wl1; out = blockIdx.y ? o1r : o1l; }
    else { W = blockIdx.y ? Wr2 : Wl2; out = blockIdx.y ? o2r : o2l; }
    int g = blockIdx.x * 256 + threadIdx.x;
    int nchunks = (Nn / 16) * 4;
    int chunk = g >> 6, lane = g & 63;
    if (chunk >= nchunks) return;
    int nf = chunk >> 2, kk = chunk & 3;
    short8 s;
#pragma unroll
    for (int j = 0; j < 8; j++) {
        float v = W[(size_t)(kk * 32 + (lane >> 4) * 8 + j) * Nn + nf * 16 + (lane & 15)];
        s[j] = (short)f2bf(v);
    }
    *(short8*)&out[((size_t)(chunk << 6) + lane) * 8] = s;
}

// ---------------- fused dual MFMA GEMM + on-the-fly BN/ReLU/cvt on A ----------------
// A is f32 [M][128]. BN=true: a = relu(A*scale+shift) per column, then bf16.
// Yb(bf16) = a@Wl ; Z(f32) = a@Wr.

template <int TN, bool BN>
__global__ __launch_bounds__(TN == 128 ? 256 : 128)
void gemm2_mfma(const float* __restrict__ A, const short* __restrict__ WlF,
                const short* __restrict__ WrF, ushort_t* __restrict__ Yb,
                float* __restrict__ Z, const float* __restrict__ stats,
                const float* __restrict__ gamma, const float* __restrict__ beta, int M) {
    __shared__ short As[64 * 136];
    __shared__ float sc[128], sh[128];
    const int tid = threadIdx.x;
    const int lane = tid & 63;
    const int w = tid >> 6;
    const int row0 = blockIdx.x * 64;
    const int NT = (TN == 128) ? 256 : 128;

    if (BN) {
        if (tid < 128) {
            float invM = 1.0f / (float)M;
            float mu = stats[tid] * invM;
            float var = stats[128 + tid] * invM - mu * mu;
            float scale = gamma[tid] * rsqrtf(var + BN_EPS);
            sc[tid] = scale;
            sh[tid] = beta[tid] - mu * scale;
        }
        __syncthreads();
    }

    for (int c = tid; c < 1024; c += NT) {
        int r = c >> 4, off = (c & 15) * 8;
        short8 v8 = {0, 0, 0, 0, 0, 0, 0, 0};
        if (row0 + r < M) {
            const float* ap = &A[(size_t)(row0 + r) * 128 + off];
            f32x4 f0 = ntload4(ap);
            f32x4 f1 = ntload4(ap + 4);
            if (BN) {
#pragma unroll
                for (int j = 0; j < 4; j++) {
                    f0[j] = fmaxf(f0[j] * sc[off + j] + sh[off + j], 0.f);
                    f1[j] = fmaxf(f1[j] * sc[off + 4 + j] + sh[off + 4 + j], 0.f);
                }
            }
#pragma unroll
            for (int j = 0; j < 4; j++) {
                v8[j] = (short)f2bf(f0[j]);
                v8[4 + j] = (short)f2bf(f1[j]);
            }
        }
        *(short8*)&As[r * 136 + off] = v8;
    }
    __syncthreads();

    const short* WF;
    bool isY;
    int col0;
    if (TN == 128) {
        isY = (w < 2);
        WF = isY ? WlF : WrF;
        col0 = (w & 1) * 64;
    } else {
        isY = (w == 0);
        WF = isY ? WlF : WrF;
        col0 = 0;
    }

    short8 a[4][4];
#pragma unroll
    for (int m = 0; m < 4; m++)
#pragma unroll
        for (int kk = 0; kk < 4; kk++)
            a[m][kk] = *(const short8*)&As[(m * 16 + (lane & 15)) * 136 + kk * 32 + (lane >> 4) * 8];

    f32x4 acc[4][4];
#pragma unroll
    for (int m = 0; m < 4; m++)
#pragma unroll
        for (int n = 0; n < 4; n++) acc[m][n] = (f32x4){0.f, 0.f, 0.f, 0.f};

#pragma unroll
    for (int kk = 0; kk < 4; kk++) {
#pragma unroll
        for (int n = 0; n < 4; n++) {
            short8 b = *(const short8*)&WF[(size_t)(((col0 >> 4) + n) * 4 + kk) * 512 + lane * 8];
#pragma unroll
            for (int m = 0; m < 4; m++)
                acc[m][n] = __builtin_amdgcn_mfma_f32_16x16x32_bf16(a[m][kk], b, acc[m][n], 0, 0, 0);
        }
    }

    // C/D: col = lane&15, row = (lane>>4)*4 + reg
#pragma unroll
    for (int m = 0; m < 4; m++) {
#pragma unroll
        for (int i = 0; i < 4; i++) {
            int gr = row0 + m * 16 + (lane >> 4) * 4 + i;
            if (gr < M) {
                if (isY) {
#pragma unroll
                    for (int n = 0; n < 4; n++)
                        Yb[(size_t)gr * TN + col0 + n * 16 + (lane & 15)] = f2bf(acc[m][n][i]);
                } else {
#pragma unroll
                    for (int n = 0; n < 4; n++)
                        Z[(size_t)gr * TN + col0 + n * 16 + (lane & 15)] = acc[m][n][i];
                }
            }
        }
    }
}

// ---------------- aggregation (layers 0/1): H[node] += mean(Yb[srcs]) + bias ----------------

__global__ __launch_bounds__(256) void agg128_kernel(const ushort_t* __restrict__ Yb,
                                                     const int* __restrict__ offs,
                                                     const ushort_t* __restrict__ sorted_src,
                                                     const float* __restrict__ bias,
                                                     float* __restrict__ H, int N) {
    int node = blockIdx.x * 4 + (threadIdx.x >> 6);
    int lane = threadIdx.x & 63;
    if (node >= N) return;
    int s0 = offs[node], s1 = offs[node + 1];
    float a0 = 0.f, a1 = 0.f;
    int k = s0;
    for (; k + 4 <= s1; k += 4) {
        int i0 = __builtin_nontemporal_load(&sorted_src[k]);
        int i1 = __builtin_nontemporal_load(&sorted_src[k + 1]);
        int i2 = __builtin_nontemporal_load(&sorted_src[k + 2]);
        int i3 = __builtin_nontemporal_load(&sorted_src[k + 3]);
        uint_t v0 = *(const uint_t*)&Yb[(size_t)i0 * 128 + lane * 2];
        uint_t v1 = *(const uint_t*)&Yb[(size_t)i1 * 128 + lane * 2];
        uint_t v2 = *(const uint_t*)&Yb[(size_t)i2 * 128 + lane * 2];
        uint_t v3 = *(const uint_t*)&Yb[(size_t)i3 * 128 + lane * 2];
        a0 += bf16lo(v0) + bf16lo(v1) + bf16lo(v2) + bf16lo(v3);
        a1 += bf16hi(v0) + bf16hi(v1) + bf16hi(v2) + bf16hi(v3);
    }
    for (; k < s1; k++) {
        uint_t v = *(const uint_t*)&Yb[(size_t)sorted_src[k] * 128 + lane * 2];
        a0 += bf16lo(v);
        a1 += bf16hi(v);
    }
    float inv = 1.0f / fmaxf((float)(s1 - s0), 1.0f);
    float2 b = *(const float2*)&bias[lane * 2];
    f32x2* hp = (f32x2*)&H[(size_t)node * 128 + lane * 2];
    f32x2 h = __builtin_nontemporal_load(hp);
    h[0] += a0 * inv + b.x;
    h[1] += a1 * inv + b.y;
    __builtin_nontemporal_store(h, hp);
}

// ---------------- layer 2: agg + bias + log_softmax fused, writes d_out ----------------

__global__ __launch_bounds__(256) void agg_lsm_kernel(const ushort_t* __restrict__ Yb,
                                                      const int* __restrict__ offs,
                                                      const ushort_t* __restrict__ sorted_src,
                                                      const float* __restrict__ bias,
                                                      const float* __restrict__ Z,
                                                      float* __restrict__ out, int N) {
    int node = blockIdx.x * 4 + (threadIdx.x >> 6);
    int lane = threadIdx.x & 63;
    int half = lane >> 5, l = lane & 31;
    if (node >= N) return;
    int s0 = offs[node], s1 = offs[node + 1];
    float a0 = 0.f, a1 = 0.f;
    for (int k = s0 + half; k < s1; k += 2) {
        uint_t v = *(const uint_t*)&Yb[(size_t)__builtin_nontemporal_load(&sorted_src[k]) * 64 + l * 2];
        a0 += bf16lo(v);
        a1 += bf16hi(v);
    }
    a0 += __shfl_xor(a0, 32);
    a1 += __shfl_xor(a1, 32);
    float inv = 1.0f / fmaxf((float)(s1 - s0), 1.0f);
    f32x2 zb = __builtin_nontemporal_load((const f32x2*)&Z[(size_t)node * 64 + l * 2]);
    float2 bb = *(const float2*)&bias[l * 2];
    float v0 = zb[0] + a0 * inv + bb.x;
    float v1 = zb[1] + a1 * inv + bb.y;
    float m = fmaxf(v0, v1);
#pragma unroll
    for (int off = 16; off; off >>= 1) m = fmaxf(m, __shfl_xor(m, off));
    float s = expf(v0 - m) + expf(v1 - m);
#pragma unroll
    for (int off = 16; off; off >>= 1) s += __shfl_xor(s, off);
    float ls = logf(s);
    if (half == 0) {
        f32x2 o;
        o[0] = v0 - m - ls;
        o[1] = v1 - m - ls;
        __builtin_nontemporal_store(o, (f32x2*)&out[(size_t)node * 64 + l * 2]);
    }
}

// ---------------- BatchNorm stats: two-stage column reduction ----------------

__global__ __launch_bounds__(256) void bn_part_kernel(const float* __restrict__ H,
                                                      float* __restrict__ P, int M) {
    int b = blockIdx.x;
    int R = (M + NB_PART - 1) / NB_PART;
    int r0 = b * R, r1 = min(r0 + R, M);
    int colg = (threadIdx.x & 31) * 4;
    int rowoff = threadIdx.x >> 5;
    f32x4 s = {0.f, 0.f, 0.f, 0.f}, s2 = {0.f, 0.f, 0.f, 0.f};
    for (int r = r0 + rowoff; r < r1; r += 8) {
        f32x4 v = ntload4(&H[(size_t)r * 128 + colg]);
        s += v;
        s2 += v * v;
    }
    __shared__ float ls[256][8];
#pragma unroll
    for (int j = 0; j < 4; j++) {
        ls[threadIdx.x][j] = s[j];
        ls[threadIdx.x][4 + j] = s2[j];
    }
    __syncthreads();
    if (threadIdx.x < 32) {
#pragma unroll
        for (int j = 0; j < 8; j++) {
            float a = 0.f;
#pragma unroll
            for (int k = 0; k < 8; k++) a += ls[threadIdx.x + 32 * k][j];
            if (j < 4) P[(size_t)b * 256 + threadIdx.x * 4 + j] = a;
            else P[(size_t)b * 256 + 128 + threadIdx.x * 4 + (j - 4)] = a;
        }
    }
}

__global__ __launch_bounds__(1024) void bn_reduce_kernel(const float* __restrict__ P,
                                                         float* __restrict__ stats) {
    int c = threadIdx.x & 255, q = threadIdx.x >> 8;
    float acc = 0.f;
    for (int i = q * (NB_PART / 4); i < (q + 1) * (NB_PART / 4); i++)
        acc += P[(size_t)i * 256 + c];
    __shared__ float ls[4][256];
    ls[q][c] = acc;
    __syncthreads();
    if (threadIdx.x < 256) stats[c] = ls[0][c] + ls[1][c] + ls[2][c] + ls[3][c];
}

// ---------------- launch ----------------

extern "C" void kernel_launch(void* const* d_in, const int* in_sizes, int n_in,
                              void* d_out, int out_size, void* d_ws, size_t ws_size,
                              hipStream_t stream) {
    const float* x   = (const float*)d_in[0];
    const int*   ei  = (const int*)d_in[1];
    const float* Wl0 = (const float*)d_in[2];
    const float* Wr0 = (const float*)d_in[3];
    const float* b0  = (const float*)d_in[4];
    const float* g0  = (const float*)d_in[5];
    const float* be0 = (const float*)d_in[6];
    const float* Wl1 = (const float*)d_in[7];
    const float* Wr1 = (const float*)d_in[8];
    const float* b1  = (const float*)d_in[9];
    const float* g1  = (const float*)d_in[10];
    const float* be1 = (const float*)d_in[11];
    const float* Wl2 = (const float*)d_in[12];
    const float* Wr2 = (const float*)d_in[13];
    const float* b2  = (const float*)d_in[14];

    const int N = in_sizes[0] / D_IN;   // 50000
    const int E = in_sizes[1] / 2;      // 800000
    const int PB = (N + 255) / 256;     // 196

    // workspace layout
    float* H = (float*)d_ws;                               // N*128 f32
    float* Z2 = H + (size_t)N * D_IN;                      // N*64 f32
    ushort_t* Yb = (ushort_t*)(Z2 + (size_t)N * D_OUT);    // N*128 bf16
    int* cnt    = (int*)(Yb + (size_t)N * D_IN);
    int* offs   = cnt + N;
    int* cursor = offs + N + 1;
    int* bsum   = cursor + N;
    int* bpre   = bsum + 256;
    ushort_t* sorted = (ushort_t*)(bpre + 256);            // E ushort
    float* stats = (float*)(sorted + E + (E & 1));         // 512 f32 (2 layers)
    float* P = stats + 512;                                // NB_PART*256 f32
    short* WlF0 = (short*)(P + NB_PART * 256);
    short* WrF0 = WlF0 + 16384;
    short* WlF1 = WrF0 + 16384;
    short* WrF1 = WlF1 + 16384;
    short* WlF2 = WrF1 + 16384;
    short* WrF2 = WlF2 + 8192;

    const int eb = (E + 255) / 256;

    // ---- CSR build ----
    hipMemsetAsync(cnt, 0, (size_t)N * sizeof(int), stream);
    hist_kernel<<<eb, 256, 0, stream>>>(ei + E, cnt, E);
    scan_part_kernel<<<PB, 256, 0, stream>>>(cnt, bsum, N);
    scan_mid_kernel<<<1, 256, 0, stream>>>(bsum, bpre, offs, PB, N);
    scan_final_kernel<<<PB, 256, 0, stream>>>(cnt, bpre, offs, N);
    hipMemcpyAsync(cursor, offs, (size_t)N * sizeof(int), hipMemcpyDeviceToDevice, stream);
    scatter_kernel<<<dim3(eb, 2), 256, 0, stream>>>(ei, ei + E, cursor, sorted, E, (N + 1) / 2);

    // ---- weight swizzle ----
    wswz_kernel<<<dim3(8, 2, 3), 256, 0, stream>>>(Wl0, Wr0, Wl1, Wr1, Wl2, Wr2,
                                                   WlF0, WrF0, WlF1, WrF1, WlF2, WrF2);

    const int gb = (N + 63) / 64;   // 782
    const int ab = (N + 3) / 4;     // 12500

    // ---- layer 0: gemm reads x f32 directly (cvt in staging) ----
    gemm2_mfma<128, false><<<gb, 256, 0, stream>>>(x, WlF0, WrF0, Yb, H,
                                                   nullptr, nullptr, nullptr, N);
    agg128_kernel<<<ab, 256, 0, stream>>>(Yb, offs, sorted, b0, H, N);
    bn_part_kernel<<<NB_PART, 256, 0, stream>>>(H, P, N);
    bn_reduce_kernel<<<1, 1024, 0, stream>>>(P, stats);

    // ---- layer 1: BN0+ReLU fused into gemm A-staging; in-place Z write ----
    gemm2_mfma<128, true><<<gb, 256, 0, stream>>>(H, WlF1, WrF1, Yb, H,
                                                  stats, g0, be0, N);
    agg128_kernel<<<ab, 256, 0, stream>>>(Yb, offs, sorted, b1, H, N);
    bn_part_kernel<<<NB_PART, 256, 0, stream>>>(H, P, N);
    bn_reduce_kernel<<<1, 1024, 0, stream>>>(P, stats + 256);

    // ---- layer 2: BN1+ReLU fused; agg + bias + log_softmax fused ----
    gemm2_mfma<64, true><<<gb, 128, 0, stream>>>(H, WlF2, WrF2, Yb, Z2,
                                                 stats + 256, g1, be1, N);
    agg_lsm_kernel<<<ab, 256, 0, stream>>>(Yb, offs, sorted, b2, Z2, (float*)d_out, N);
}

// Round 6
// 372.777 us; speedup vs baseline: 2.0309x; 1.1145x over previous
//
#include <hip/hip_runtime.h>
#include <hip/hip_bf16.h>

#define D_IN 128
#define D_OUT 64
#define BN_EPS 1e-5f
#define NB_PART 512

typedef short short8 __attribute__((ext_vector_type(8)));
typedef float f32x4 __attribute__((ext_vector_type(4)));
typedef float f32x2 __attribute__((ext_vector_type(2)));
typedef unsigned short ushort_t;
typedef unsigned int uint_t;

__device__ __forceinline__ float bf16lo(uint_t v) { return __uint_as_float(v << 16); }
__device__ __forceinline__ float bf16hi(uint_t v) { return __uint_as_float(v & 0xffff0000u); }
__device__ __forceinline__ ushort_t f2bf(float f) {
    union { __hip_bfloat16 h; ushort_t u; } cv;
    cv.h = __float2bfloat16(f);
    return cv.u;
}
__device__ __forceinline__ f32x4 ntload4(const float* p) {
    return __builtin_nontemporal_load((const f32x4*)p);
}

// ---------------- CSR construction ----------------

__global__ void hist_kernel(const int* __restrict__ dst, int* __restrict__ cnt, int E) {
    int i = blockIdx.x * 256 + threadIdx.x;
    if (i < E) atomicAdd(&cnt[__builtin_nontemporal_load(&dst[i])], 1);
}

__global__ void scan_part_kernel(const int* __restrict__ cnt, int* __restrict__ bsum, int n) {
    int i = blockIdx.x * 256 + threadIdx.x;
    int v = (i < n) ? cnt[i] : 0;
#pragma unroll
    for (int off = 1; off < 64; off <<= 1) v += __shfl_xor(v, off);
    __shared__ int ws[4];
    int lane = threadIdx.x & 63, wid = threadIdx.x >> 6;
    if (lane == 0) ws[wid] = v;
    __syncthreads();
    if (threadIdx.x == 0) bsum[blockIdx.x] = ws[0] + ws[1] + ws[2] + ws[3];
}

__global__ void scan_mid_kernel(const int* __restrict__ bsum, int* __restrict__ bpre,
                                int* __restrict__ offs, int PB, int n) {
    int t = threadIdx.x;
    int v = (t < PB) ? bsum[t] : 0;
    int lane = t & 63, wid = t >> 6;
    int sc = v;
#pragma unroll
    for (int off = 1; off < 64; off <<= 1) {
        int u = __shfl_up(sc, off);
        if (lane >= off) sc += u;
    }
    __shared__ int ws[4];
    if (lane == 63) ws[wid] = sc;
    __syncthreads();
    int wb = 0;
    for (int w = 0; w < 4; w++) if (w < wid) wb += ws[w];
    int incl = sc + wb;
    if (t < PB) bpre[t] = incl - v;
    if (t == PB - 1) offs[n] = incl;
}

// writes offs AND cursor (saves a d2d copy dispatch)
__global__ void scan_final_kernel(const int* __restrict__ cnt, const int* __restrict__ bpre,
                                  int* __restrict__ offs, int* __restrict__ cursor, int n) {
    int b = blockIdx.x, t = threadIdx.x;
    int i = b * 256 + t;
    int v = (i < n) ? cnt[i] : 0;
    int lane = t & 63, wid = t >> 6;
    int sc = v;
#pragma unroll
    for (int off = 1; off < 64; off <<= 1) {
        int u = __shfl_up(sc, off);
        if (lane >= off) sc += u;
    }
    __shared__ int ws[4];
    if (lane == 63) ws[wid] = sc;
    __syncthreads();
    int wb = 0;
    for (int w = 0; w < 4; w++) if (w < wid) wb += ws[w];
    if (i < n) {
        int e = bpre[b] + wb + sc - v;
        offs[i] = e;
        cursor[i] = e;
    }
}

__global__ void scatter_kernel(const int* __restrict__ src, const int* __restrict__ dst,
                               int* __restrict__ cursor, ushort_t* __restrict__ sorted_src,
                               int E, int passW) {
    int lo = blockIdx.y * passW, hi = lo + passW;
    int i = blockIdx.x * 256 + threadIdx.x;
    if (i < E) {
        int d = __builtin_nontemporal_load(&dst[i]);
        if (d >= lo && d < hi) {
            int s = __builtin_nontemporal_load(&src[i]);
            int p = atomicAdd(&cursor[d], 1);
            sorted_src[p] = (ushort_t)s;
        }
    }
}

// ---------------- weight swizzle (all 3 layers in one launch) ----------------
// chunk (nf, kk): 64 lanes x 8 bf16; lane l elem j = W[kk*32 + (l>>4)*8 + j][nf*16 + (l&15)]

__global__ void wswz_kernel(const float* __restrict__ Wl0, const float* __restrict__ Wr0,
                            const float* __restrict__ Wl1, const float* __restrict__ Wr1,
                            const float* __restrict__ Wl2, const float* __restrict__ Wr2,
                            short* __restrict__ o0l, short* __restrict__ o0r,
                            short* __restrict__ o1l, short* __restrict__ o1r,
                            short* __restrict__ o2l, short* __restrict__ o2r) {
    int layer = blockIdx.z;
    int Nn = (layer == 2) ? 64 : 128;
    const float* W;
    short* out;
    if (layer == 0) { W = blockIdx.y ? Wr0 : Wl0; out = blockIdx.y ? o0r : o0l; }
    else if (layer == 1) { W = blockIdx.y ? Wr1 : Wl1; out = blockIdx.y ? o1r : o1l; }
    else { W = blockIdx.y ? Wr2 : Wl2; out = blockIdx.y ? o2r : o2l; }
    int g = blockIdx.x * 256 + threadIdx.x;
    int nchunks = (Nn / 16) * 4;
    int chunk = g >> 6, lane = g & 63;
    if (chunk >= nchunks) return;
    int nf = chunk >> 2, kk = chunk & 3;
    short8 s;
#pragma unroll
    for (int j = 0; j < 8; j++) {
        float v = W[(size_t)(kk * 32 + (lane >> 4) * 8 + j) * Nn + nf * 16 + (lane & 15)];
        s[j] = (short)f2bf(v);
    }
    *(short8*)&out[((size_t)(chunk << 6) + lane) * 8] = s;
}

// ---------------- fused dual MFMA GEMM + on-the-fly BN/ReLU/cvt on A ----------------

template <int TN, bool BN>
__global__ __launch_bounds__(TN == 128 ? 256 : 128)
void gemm2_mfma(const float* __restrict__ A, const short* __restrict__ WlF,
                const short* __restrict__ WrF, ushort_t* __restrict__ Yb,
                float* __restrict__ Z, const float* __restrict__ stats,
                const float* __restrict__ gamma, const float* __restrict__ beta, int M) {
    __shared__ short As[64 * 136];
    __shared__ float sc[128], sh[128];
    const int tid = threadIdx.x;
    const int lane = tid & 63;
    const int w = tid >> 6;
    const int row0 = blockIdx.x * 64;
    const int NT = (TN == 128) ? 256 : 128;

    if (BN) {
        if (tid < 128) {
            float invM = 1.0f / (float)M;
            float mu = stats[tid] * invM;
            float var = stats[128 + tid] * invM - mu * mu;
            float scale = gamma[tid] * rsqrtf(var + BN_EPS);
            sc[tid] = scale;
            sh[tid] = beta[tid] - mu * scale;
        }
        __syncthreads();
    }

    for (int c = tid; c < 1024; c += NT) {
        int r = c >> 4, off = (c & 15) * 8;
        short8 v8 = {0, 0, 0, 0, 0, 0, 0, 0};
        if (row0 + r < M) {
            const float* ap = &A[(size_t)(row0 + r) * 128 + off];
            f32x4 f0 = ntload4(ap);
            f32x4 f1 = ntload4(ap + 4);
            if (BN) {
#pragma unroll
                for (int j = 0; j < 4; j++) {
                    f0[j] = fmaxf(f0[j] * sc[off + j] + sh[off + j], 0.f);
                    f1[j] = fmaxf(f1[j] * sc[off + 4 + j] + sh[off + 4 + j], 0.f);
                }
            }
#pragma unroll
            for (int j = 0; j < 4; j++) {
                v8[j] = (short)f2bf(f0[j]);
                v8[4 + j] = (short)f2bf(f1[j]);
            }
        }
        *(short8*)&As[r * 136 + off] = v8;
    }
    __syncthreads();

    const short* WF;
    bool isY;
    int col0;
    if (TN == 128) {
        isY = (w < 2);
        WF = isY ? WlF : WrF;
        col0 = (w & 1) * 64;
    } else {
        isY = (w == 0);
        WF = isY ? WlF : WrF;
        col0 = 0;
    }

    short8 a[4][4];
#pragma unroll
    for (int m = 0; m < 4; m++)
#pragma unroll
        for (int kk = 0; kk < 4; kk++)
            a[m][kk] = *(const short8*)&As[(m * 16 + (lane & 15)) * 136 + kk * 32 + (lane >> 4) * 8];

    f32x4 acc[4][4];
#pragma unroll
    for (int m = 0; m < 4; m++)
#pragma unroll
        for (int n = 0; n < 4; n++) acc[m][n] = (f32x4){0.f, 0.f, 0.f, 0.f};

#pragma unroll
    for (int kk = 0; kk < 4; kk++) {
#pragma unroll
        for (int n = 0; n < 4; n++) {
            short8 b = *(const short8*)&WF[(size_t)(((col0 >> 4) + n) * 4 + kk) * 512 + lane * 8];
#pragma unroll
            for (int m = 0; m < 4; m++)
                acc[m][n] = __builtin_amdgcn_mfma_f32_16x16x32_bf16(a[m][kk], b, acc[m][n], 0, 0, 0);
        }
    }

    // C/D: col = lane&15, row = (lane>>4)*4 + reg
#pragma unroll
    for (int m = 0; m < 4; m++) {
#pragma unroll
        for (int i = 0; i < 4; i++) {
            int gr = row0 + m * 16 + (lane >> 4) * 4 + i;
            if (gr < M) {
                if (isY) {
#pragma unroll
                    for (int n = 0; n < 4; n++)
                        Yb[(size_t)gr * TN + col0 + n * 16 + (lane & 15)] = f2bf(acc[m][n][i]);
                } else {
#pragma unroll
                    for (int n = 0; n < 4; n++)
                        Z[(size_t)gr * TN + col0 + n * 16 + (lane & 15)] = acc[m][n][i];
                }
            }
        }
    }
}

// ---------------- aggregation (layers 0/1): H[node] += mean(Yb[srcs]) + bias ----------------
// one wave per node; 8 gathers in flight

__global__ __launch_bounds__(256) void agg128_kernel(const ushort_t* __restrict__ Yb,
                                                     const int* __restrict__ offs,
                                                     const ushort_t* __restrict__ sorted_src,
                                                     const float* __restrict__ bias,
                                                     float* __restrict__ H, int N) {
    int node = blockIdx.x * 4 + (threadIdx.x >> 6);
    int lane = threadIdx.x & 63;
    if (node >= N) return;
    int s0 = offs[node], s1 = offs[node + 1];
    float a0 = 0.f, a1 = 0.f;
    int k = s0;
    for (; k + 8 <= s1; k += 8) {
        int idx[8];
#pragma unroll
        for (int j = 0; j < 8; j++) idx[j] = __builtin_nontemporal_load(&sorted_src[k + j]);
        uint_t v[8];
#pragma unroll
        for (int j = 0; j < 8; j++) v[j] = *(const uint_t*)&Yb[(size_t)idx[j] * 128 + lane * 2];
#pragma unroll
        for (int j = 0; j < 8; j++) {
            a0 += bf16lo(v[j]);
            a1 += bf16hi(v[j]);
        }
    }
    if (k + 4 <= s1) {
        int idx[4];
#pragma unroll
        for (int j = 0; j < 4; j++) idx[j] = __builtin_nontemporal_load(&sorted_src[k + j]);
#pragma unroll
        for (int j = 0; j < 4; j++) {
            uint_t v = *(const uint_t*)&Yb[(size_t)idx[j] * 128 + lane * 2];
            a0 += bf16lo(v);
            a1 += bf16hi(v);
        }
        k += 4;
    }
    for (; k < s1; k++) {
        uint_t v = *(const uint_t*)&Yb[(size_t)sorted_src[k] * 128 + lane * 2];
        a0 += bf16lo(v);
        a1 += bf16hi(v);
    }
    float inv = 1.0f / fmaxf((float)(s1 - s0), 1.0f);
    float2 b = *(const float2*)&bias[lane * 2];
    f32x2* hp = (f32x2*)&H[(size_t)node * 128 + lane * 2];
    f32x2 h = __builtin_nontemporal_load(hp);
    h[0] += a0 * inv + b.x;
    h[1] += a1 * inv + b.y;
    __builtin_nontemporal_store(h, hp);
}

// ---------------- layer 2: agg + bias + log_softmax fused ----------------
// one wave = TWO nodes (one per 32-lane half); 4-deep gather unroll

__global__ __launch_bounds__(256) void agg_lsm_kernel(const ushort_t* __restrict__ Yb,
                                                      const int* __restrict__ offs,
                                                      const ushort_t* __restrict__ sorted_src,
                                                      const float* __restrict__ bias,
                                                      const float* __restrict__ Z,
                                                      float* __restrict__ out, int N) {
    int wv = blockIdx.x * 4 + (threadIdx.x >> 6);
    int lane = threadIdx.x & 63;
    int half = lane >> 5, l = lane & 31;
    int node = wv * 2 + half;
    if (node >= N) return;
    int s0 = offs[node], s1 = offs[node + 1];
    float a0 = 0.f, a1 = 0.f;
    int k = s0;
    for (; k + 4 <= s1; k += 4) {
        int idx[4];
#pragma unroll
        for (int j = 0; j < 4; j++) idx[j] = __builtin_nontemporal_load(&sorted_src[k + j]);
#pragma unroll
        for (int j = 0; j < 4; j++) {
            uint_t v = *(const uint_t*)&Yb[(size_t)idx[j] * 64 + l * 2];
            a0 += bf16lo(v);
            a1 += bf16hi(v);
        }
    }
    for (; k < s1; k++) {
        uint_t v = *(const uint_t*)&Yb[(size_t)sorted_src[k] * 64 + l * 2];
        a0 += bf16lo(v);
        a1 += bf16hi(v);
    }
    float inv = 1.0f / fmaxf((float)(s1 - s0), 1.0f);
    f32x2 zb = __builtin_nontemporal_load((const f32x2*)&Z[(size_t)node * 64 + l * 2]);
    float2 bb = *(const float2*)&bias[l * 2];
    float v0 = zb[0] + a0 * inv + bb.x;
    float v1 = zb[1] + a1 * inv + bb.y;
    // reductions stay within the 32-lane half (xor offsets <= 16)
    float m = fmaxf(v0, v1);
#pragma unroll
    for (int off = 16; off; off >>= 1) m = fmaxf(m, __shfl_xor(m, off));
    float s = expf(v0 - m) + expf(v1 - m);
#pragma unroll
    for (int off = 16; off; off >>= 1) s += __shfl_xor(s, off);
    float ls = logf(s);
    f32x2 o;
    o[0] = v0 - m - ls;
    o[1] = v1 - m - ls;
    __builtin_nontemporal_store(o, (f32x2*)&out[(size_t)node * 64 + l * 2]);
}

// ---------------- BatchNorm stats: two-stage column reduction ----------------

__global__ __launch_bounds__(256) void bn_part_kernel(const float* __restrict__ H,
                                                      float* __restrict__ P, int M) {
    int b = blockIdx.x;
    int R = (M + NB_PART - 1) / NB_PART;
    int r0 = b * R, r1 = min(r0 + R, M);
    int colg = (threadIdx.x & 31) * 4;
    int rowoff = threadIdx.x >> 5;
    f32x4 s = {0.f, 0.f, 0.f, 0.f}, s2 = {0.f, 0.f, 0.f, 0.f};
    for (int r = r0 + rowoff; r < r1; r += 8) {
        f32x4 v = ntload4(&H[(size_t)r * 128 + colg]);
        s += v;
        s2 += v * v;
    }
    __shared__ float ls[256][8];
#pragma unroll
    for (int j = 0; j < 4; j++) {
        ls[threadIdx.x][j] = s[j];
        ls[threadIdx.x][4 + j] = s2[j];
    }
    __syncthreads();
    if (threadIdx.x < 32) {
#pragma unroll
        for (int j = 0; j < 8; j++) {
            float a = 0.f;
#pragma unroll
            for (int k = 0; k < 8; k++) a += ls[threadIdx.x + 32 * k][j];
            if (j < 4) P[(size_t)b * 256 + threadIdx.x * 4 + j] = a;
            else P[(size_t)b * 256 + 128 + threadIdx.x * 4 + (j - 4)] = a;
        }
    }
}

__global__ __launch_bounds__(1024) void bn_reduce_kernel(const float* __restrict__ P,
                                                         float* __restrict__ stats) {
    int c = threadIdx.x & 255, q = threadIdx.x >> 8;
    float acc = 0.f;
#pragma unroll 8
    for (int i = q * (NB_PART / 4); i < (q + 1) * (NB_PART / 4); i++)
        acc += P[(size_t)i * 256 + c];
    __shared__ float ls[4][256];
    ls[q][c] = acc;
    __syncthreads();
    if (threadIdx.x < 256) stats[c] = ls[0][c] + ls[1][c] + ls[2][c] + ls[3][c];
}

// ---------------- launch ----------------

extern "C" void kernel_launch(void* const* d_in, const int* in_sizes, int n_in,
                              void* d_out, int out_size, void* d_ws, size_t ws_size,
                              hipStream_t stream) {
    const float* x   = (const float*)d_in[0];
    const int*   ei  = (const int*)d_in[1];
    const float* Wl0 = (const float*)d_in[2];
    const float* Wr0 = (const float*)d_in[3];
    const float* b0  = (const float*)d_in[4];
    const float* g0  = (const float*)d_in[5];
    const float* be0 = (const float*)d_in[6];
    const float* Wl1 = (const float*)d_in[7];
    const float* Wr1 = (const float*)d_in[8];
    const float* b1  = (const float*)d_in[9];
    const float* g1  = (const float*)d_in[10];
    const float* be1 = (const float*)d_in[11];
    const float* Wl2 = (const float*)d_in[12];
    const float* Wr2 = (const float*)d_in[13];
    const float* b2  = (const float*)d_in[14];

    const int N = in_sizes[0] / D_IN;   // 50000
    const int E = in_sizes[1] / 2;      // 800000
    const int PB = (N + 255) / 256;     // 196

    // workspace layout
    float* H = (float*)d_ws;                               // N*128 f32
    float* Z2 = H + (size_t)N * D_IN;                      // N*64 f32
    ushort_t* Yb = (ushort_t*)(Z2 + (size_t)N * D_OUT);    // N*128 bf16
    int* cnt    = (int*)(Yb + (size_t)N * D_IN);
    int* offs   = cnt + N;
    int* cursor = offs + N + 1;
    int* bsum   = cursor + N;
    int* bpre   = bsum + 256;
    ushort_t* sorted = (ushort_t*)(bpre + 256);            // E ushort
    float* stats = (float*)(sorted + E + (E & 1));         // 512 f32 (2 layers)
    float* P = stats + 512;                                // NB_PART*256 f32
    short* WlF0 = (short*)(P + NB_PART * 256);
    short* WrF0 = WlF0 + 16384;
    short* WlF1 = WrF0 + 16384;
    short* WrF1 = WlF1 + 16384;
    short* WlF2 = WrF1 + 16384;
    short* WrF2 = WlF2 + 8192;

    const int eb = (E + 255) / 256;

    // ---- CSR build ----
    hipMemsetAsync(cnt, 0, (size_t)N * sizeof(int), stream);
    hist_kernel<<<eb, 256, 0, stream>>>(ei + E, cnt, E);
    scan_part_kernel<<<PB, 256, 0, stream>>>(cnt, bsum, N);
    scan_mid_kernel<<<1, 256, 0, stream>>>(bsum, bpre, offs, PB, N);
    scan_final_kernel<<<PB, 256, 0, stream>>>(cnt, bpre, offs, cursor, N);
    scatter_kernel<<<dim3(eb, 2), 256, 0, stream>>>(ei, ei + E, cursor, sorted, E, (N + 1) / 2);

    // ---- weight swizzle ----
    wswz_kernel<<<dim3(8, 2, 3), 256, 0, stream>>>(Wl0, Wr0, Wl1, Wr1, Wl2, Wr2,
                                                   WlF0, WrF0, WlF1, WrF1, WlF2, WrF2);

    const int gb = (N + 63) / 64;   // 782
    const int ab = (N + 3) / 4;     // 12500
    const int ab2 = (N + 7) / 8;    // 6250

    // ---- layer 0 ----
    gemm2_mfma<128, false><<<gb, 256, 0, stream>>>(x, WlF0, WrF0, Yb, H,
                                                   nullptr, nullptr, nullptr, N);
    agg128_kernel<<<ab, 256, 0, stream>>>(Yb, offs, sorted, b0, H, N);
    bn_part_kernel<<<NB_PART, 256, 0, stream>>>(H, P, N);
    bn_reduce_kernel<<<1, 1024, 0, stream>>>(P, stats);

    // ---- layer 1 ----
    gemm2_mfma<128, true><<<gb, 256, 0, stream>>>(H, WlF1, WrF1, Yb, H,
                                                  stats, g0, be0, N);
    agg128_kernel<<<ab, 256, 0, stream>>>(Yb, offs, sorted, b1, H, N);
    bn_part_kernel<<<NB_PART, 256, 0, stream>>>(H, P, N);
    bn_reduce_kernel<<<1, 1024, 0, stream>>>(P, stats + 256);

    // ---- layer 2 ----
    gemm2_mfma<64, true><<<gb, 128, 0, stream>>>(H, WlF2, WrF2, Yb, Z2,
                                                 stats + 256, g1, be1, N);
    agg_lsm_kernel<<<ab2, 256, 0, stream>>>(Yb, offs, sorted, b2, Z2, (float*)d_out, N);
}

// Round 9
// 347.514 us; speedup vs baseline: 2.1785x; 1.0727x over previous
//
#include <hip/hip_runtime.h>
#include <hip/hip_bf16.h>

#define D_IN 128
#define D_OUT 64
#define BN_EPS 1e-5f
#define NB_PART 512

typedef short short8 __attribute__((ext_vector_type(8)));
typedef float f32x4 __attribute__((ext_vector_type(4)));
typedef float f32x2 __attribute__((ext_vector_type(2)));
typedef unsigned int u32x4 __attribute__((ext_vector_type(4)));
typedef unsigned int u32x2 __attribute__((ext_vector_type(2)));
typedef unsigned short ushort_t;
typedef unsigned int uint_t;

__device__ __forceinline__ float bf16lo(uint_t v) { return __uint_as_float(v << 16); }
__device__ __forceinline__ float bf16hi(uint_t v) { return __uint_as_float(v & 0xffff0000u); }
__device__ __forceinline__ float bf2f(ushort_t u) { return __uint_as_float(((uint_t)u) << 16); }
__device__ __forceinline__ ushort_t f2bf(float f) {
    union { __hip_bfloat16 h; ushort_t u; } cv;
    cv.h = __float2bfloat16(f);
    return cv.u;
}
__device__ __forceinline__ f32x4 ntload4(const float* p) {
    return __builtin_nontemporal_load((const f32x4*)p);
}

// ---------------- CSR construction ----------------

__global__ void hist_kernel(const int* __restrict__ dst, int* __restrict__ cnt, int E) {
    int i = blockIdx.x * 256 + threadIdx.x;
    if (i < E) atomicAdd(&cnt[__builtin_nontemporal_load(&dst[i])], 1);
}

__global__ void scan_part_kernel(const int* __restrict__ cnt, int* __restrict__ bsum, int n) {
    int i = blockIdx.x * 256 + threadIdx.x;
    int v = (i < n) ? cnt[i] : 0;
#pragma unroll
    for (int off = 1; off < 64; off <<= 1) v += __shfl_xor(v, off);
    __shared__ int ws[4];
    int lane = threadIdx.x & 63, wid = threadIdx.x >> 6;
    if (lane == 0) ws[wid] = v;
    __syncthreads();
    if (threadIdx.x == 0) bsum[blockIdx.x] = ws[0] + ws[1] + ws[2] + ws[3];
}

__global__ void scan_mid_kernel(const int* __restrict__ bsum, int* __restrict__ bpre,
                                int* __restrict__ offs, int PB, int n) {
    int t = threadIdx.x;
    int v = (t < PB) ? bsum[t] : 0;
    int lane = t & 63, wid = t >> 6;
    int sc = v;
#pragma unroll
    for (int off = 1; off < 64; off <<= 1) {
        int u = __shfl_up(sc, off);
        if (lane >= off) sc += u;
    }
    __shared__ int ws[4];
    if (lane == 63) ws[wid] = sc;
    __syncthreads();
    int wb = 0;
    for (int w = 0; w < 4; w++) if (w < wid) wb += ws[w];
    int incl = sc + wb;
    if (t < PB) bpre[t] = incl - v;
    if (t == PB - 1) offs[n] = incl;
}

__global__ void scan_final_kernel(const int* __restrict__ cnt, const int* __restrict__ bpre,
                                  int* __restrict__ offs, int* __restrict__ cursor, int n) {
    int b = blockIdx.x, t = threadIdx.x;
    int i = b * 256 + t;
    int v = (i < n) ? cnt[i] : 0;
    int lane = t & 63, wid = t >> 6;
    int sc = v;
#pragma unroll
    for (int off = 1; off < 64; off <<= 1) {
        int u = __shfl_up(sc, off);
        if (lane >= off) sc += u;
    }
    __shared__ int ws[4];
    if (lane == 63) ws[wid] = sc;
    __syncthreads();
    int wb = 0;
    for (int w = 0; w < 4; w++) if (w < wid) wb += ws[w];
    if (i < n) {
        int e = bpre[b] + wb + sc - v;
        offs[i] = e;
        cursor[i] = e;
    }
}

__global__ void scatter_kernel(const int* __restrict__ src, const int* __restrict__ dst,
                               int* __restrict__ cursor, ushort_t* __restrict__ sorted_src,
                               int E, int passW) {
    int lo = blockIdx.y * passW, hi = lo + passW;
    int i = blockIdx.x * 256 + threadIdx.x;
    if (i < E) {
        int d = __builtin_nontemporal_load(&dst[i]);
        if (d >= lo && d < hi) {
            int s = __builtin_nontemporal_load(&src[i]);
            int p = atomicAdd(&cursor[d], 1);
            sorted_src[p] = (ushort_t)s;
        }
    }
}

// ---------------- weight swizzle (all 3 layers in one launch) ----------------
// chunk (nf, kk): 64 lanes x 8 bf16; lane l elem j = W[kk*32 + (l>>4)*8 + j][nf*16 + (l&15)]

__global__ void wswz_kernel(const float* __restrict__ Wl0, const float* __restrict__ Wr0,
                            const float* __restrict__ Wl1, const float* __restrict__ Wr1,
                            const float* __restrict__ Wl2, const float* __restrict__ Wr2,
                            short* __restrict__ o0l, short* __restrict__ o0r,
                            short* __restrict__ o1l, short* __restrict__ o1r,
                            short* __restrict__ o2l, short* __restrict__ o2r) {
    int layer = blockIdx.z;
    int Nn = (layer == 2) ? 64 : 128;
    const float* W;
    short* out;
    if (layer == 0) { W = blockIdx.y ? Wr0 : Wl0; out = blockIdx.y ? o0r : o0l; }
    else if (layer == 1) { W = blockIdx.y ? Wr1 : Wl1; out = blockIdx.y ? o1r : o1l; }
    else { W = blockIdx.y ? Wr2 : Wl2; out = blockIdx.y ? o2r : o2l; }
    int g = blockIdx.x * 256 + threadIdx.x;
    int nchunks = (Nn / 16) * 4;
    int chunk = g >> 6, lane = g & 63;
    if (chunk >= nchunks) return;
    int nf = chunk >> 2, kk = chunk & 3;
    short8 s;
#pragma unroll
    for (int j = 0; j < 8; j++) {
        float v = W[(size_t)(kk * 32 + (lane >> 4) * 8 + j) * Nn + nf * 16 + (lane & 15)];
        s[j] = (short)f2bf(v);
    }
    *(short8*)&out[((size_t)(chunk << 6) + lane) * 8] = s;
}

// ---------------- fused dual MFMA GEMM + on-the-fly BN/ReLU on A ----------------
// BF16IN=false: A is f32 (layer 0, no BN). BF16IN=true: A is bf16 + BN+ReLU fused.
// Both outputs bf16: Yb = a@Wl, Zb = a@Wr.

template <int TN, bool BF16IN>
__global__ __launch_bounds__(TN == 128 ? 256 : 128)
void gemm2_mfma(const void* __restrict__ Ain, const short* __restrict__ WlF,
                const short* __restrict__ WrF, ushort_t* __restrict__ Yb,
                ushort_t* __restrict__ Zb, const float* __restrict__ stats,
                const float* __restrict__ gamma, const float* __restrict__ beta, int M) {
    __shared__ short As[64 * 136];
    __shared__ float sc[128], sh[128];
    const int tid = threadIdx.x;
    const int lane = tid & 63;
    const int w = tid >> 6;
    const int row0 = blockIdx.x * 64;
    const int NT = (TN == 128) ? 256 : 128;

    if (BF16IN) {
        if (tid < 128) {
            float invM = 1.0f / (float)M;
            float mu = stats[tid] * invM;
            float var = stats[128 + tid] * invM - mu * mu;
            float scale = gamma[tid] * rsqrtf(var + BN_EPS);
            sc[tid] = scale;
            sh[tid] = beta[tid] - mu * scale;
        }
        __syncthreads();
    }

    for (int c = tid; c < 1024; c += NT) {
        int r = c >> 4, off = (c & 15) * 8;
        short8 v8 = {0, 0, 0, 0, 0, 0, 0, 0};
        if (row0 + r < M) {
            if (BF16IN) {
                const ushort_t* ap = (const ushort_t*)Ain + (size_t)(row0 + r) * 128 + off;
                short8 h = *(const short8*)ap;
#pragma unroll
                for (int j = 0; j < 8; j++) {
                    float f = bf2f((ushort_t)h[j]);
                    f = fmaxf(f * sc[off + j] + sh[off + j], 0.f);
                    v8[j] = (short)f2bf(f);
                }
            } else {
                const float* ap = (const float*)Ain + (size_t)(row0 + r) * 128 + off;
                f32x4 f0 = ntload4(ap);
                f32x4 f1 = ntload4(ap + 4);
#pragma unroll
                for (int j = 0; j < 4; j++) {
                    v8[j] = (short)f2bf(f0[j]);
                    v8[4 + j] = (short)f2bf(f1[j]);
                }
            }
        }
        *(short8*)&As[r * 136 + off] = v8;
    }
    __syncthreads();

    const short* WF;
    ushort_t* D;
    int col0;
    if (TN == 128) {
        bool isY = (w < 2);
        WF = isY ? WlF : WrF;
        D = isY ? Yb : Zb;
        col0 = (w & 1) * 64;
    } else {
        bool isY = (w == 0);
        WF = isY ? WlF : WrF;
        D = isY ? Yb : Zb;
        col0 = 0;
    }

    short8 a[4][4];
#pragma unroll
    for (int m = 0; m < 4; m++)
#pragma unroll
        for (int kk = 0; kk < 4; kk++)
            a[m][kk] = *(const short8*)&As[(m * 16 + (lane & 15)) * 136 + kk * 32 + (lane >> 4) * 8];

    f32x4 acc[4][4];
#pragma unroll
    for (int m = 0; m < 4; m++)
#pragma unroll
        for (int n = 0; n < 4; n++) acc[m][n] = (f32x4){0.f, 0.f, 0.f, 0.f};

#pragma unroll
    for (int kk = 0; kk < 4; kk++) {
#pragma unroll
        for (int n = 0; n < 4; n++) {
            short8 b = *(const short8*)&WF[(size_t)(((col0 >> 4) + n) * 4 + kk) * 512 + lane * 8];
#pragma unroll
            for (int m = 0; m < 4; m++)
                acc[m][n] = __builtin_amdgcn_mfma_f32_16x16x32_bf16(a[m][kk], b, acc[m][n], 0, 0, 0);
        }
    }

    // C/D: col = lane&15, row = (lane>>4)*4 + reg
#pragma unroll
    for (int m = 0; m < 4; m++) {
#pragma unroll
        for (int i = 0; i < 4; i++) {
            int gr = row0 + m * 16 + (lane >> 4) * 4 + i;
            if (gr < M) {
#pragma unroll
                for (int n = 0; n < 4; n++)
                    D[(size_t)gr * TN + col0 + n * 16 + (lane & 15)] = f2bf(acc[m][n][i]);
            }
        }
    }
}

// ---------------- aggregation (layers 0/1): Hb[node] = Zb[node] + mean(Yb[srcs]) + bias ----
// one wave = TWO nodes (one per 32-lane half, uint2 = 4 cols/lane); 8 gathers in flight

__global__ __launch_bounds__(256) void agg128_kernel(const ushort_t* __restrict__ Yb,
                                                     const int* __restrict__ offs,
                                                     const ushort_t* __restrict__ sorted_src,
                                                     const float* __restrict__ bias,
                                                     const ushort_t* __restrict__ Zb,
                                                     ushort_t* __restrict__ Hb, int N) {
    int wv = blockIdx.x * 4 + (threadIdx.x >> 6);
    int lane = threadIdx.x & 63;
    int half = lane >> 5, l = lane & 31;
    int node = wv * 2 + half;
    if (node >= N) return;
    int s0 = offs[node], s1 = offs[node + 1];
    float a0 = 0.f, a1 = 0.f, a2 = 0.f, a3 = 0.f;
    int k = s0;
    for (; k + 8 <= s1; k += 8) {
        int idx[8];
#pragma unroll
        for (int j = 0; j < 8; j++) idx[j] = __builtin_nontemporal_load(&sorted_src[k + j]);
        u32x2 v[8];
#pragma unroll
        for (int j = 0; j < 8; j++) v[j] = *(const u32x2*)&Yb[(size_t)idx[j] * 128 + l * 4];
#pragma unroll
        for (int j = 0; j < 8; j++) {
            a0 += bf16lo(v[j][0]);
            a1 += bf16hi(v[j][0]);
            a2 += bf16lo(v[j][1]);
            a3 += bf16hi(v[j][1]);
        }
    }
    if (k + 4 <= s1) {
        int idx[4];
#pragma unroll
        for (int j = 0; j < 4; j++) idx[j] = __builtin_nontemporal_load(&sorted_src[k + j]);
#pragma unroll
        for (int j = 0; j < 4; j++) {
            u32x2 v = *(const u32x2*)&Yb[(size_t)idx[j] * 128 + l * 4];
            a0 += bf16lo(v[0]);
            a1 += bf16hi(v[0]);
            a2 += bf16lo(v[1]);
            a3 += bf16hi(v[1]);
        }
        k += 4;
    }
    for (; k < s1; k++) {
        u32x2 v = *(const u32x2*)&Yb[(size_t)sorted_src[k] * 128 + l * 4];
        a0 += bf16lo(v[0]);
        a1 += bf16hi(v[0]);
        a2 += bf16lo(v[1]);
        a3 += bf16hi(v[1]);
    }
    float inv = 1.0f / fmaxf((float)(s1 - s0), 1.0f);
    float4 bb = *(const float4*)&bias[l * 4];
    u32x2 z = __builtin_nontemporal_load((const u32x2*)&Zb[(size_t)node * 128 + l * 4]);
    float h0 = bf16lo(z[0]) + a0 * inv + bb.x;
    float h1 = bf16hi(z[0]) + a1 * inv + bb.y;
    float h2 = bf16lo(z[1]) + a2 * inv + bb.z;
    float h3 = bf16hi(z[1]) + a3 * inv + bb.w;
    u32x2 o;
    o[0] = (uint_t)f2bf(h0) | ((uint_t)f2bf(h1) << 16);
    o[1] = (uint_t)f2bf(h2) | ((uint_t)f2bf(h3) << 16);
    __builtin_nontemporal_store(o, (u32x2*)&Hb[(size_t)node * 128 + l * 4]);
}

// ---------------- layer 2: agg + bias + log_softmax fused ----------------
// one wave = TWO nodes (one per 32-lane half); 4-deep gather unroll

__global__ __launch_bounds__(256) void agg_lsm_kernel(const ushort_t* __restrict__ Yb,
                                                      const int* __restrict__ offs,
                                                      const ushort_t* __restrict__ sorted_src,
                                                      const float* __restrict__ bias,
                                                      const ushort_t* __restrict__ Zb,
                                                      float* __restrict__ out, int N) {
    int wv = blockIdx.x * 4 + (threadIdx.x >> 6);
    int lane = threadIdx.x & 63;
    int half = lane >> 5, l = lane & 31;
    int node = wv * 2 + half;
    if (node >= N) return;
    int s0 = offs[node], s1 = offs[node + 1];
    float a0 = 0.f, a1 = 0.f;
    int k = s0;
    for (; k + 4 <= s1; k += 4) {
        int idx[4];
#pragma unroll
        for (int j = 0; j < 4; j++) idx[j] = __builtin_nontemporal_load(&sorted_src[k + j]);
#pragma unroll
        for (int j = 0; j < 4; j++) {
            uint_t v = *(const uint_t*)&Yb[(size_t)idx[j] * 64 + l * 2];
            a0 += bf16lo(v);
            a1 += bf16hi(v);
        }
    }
    for (; k < s1; k++) {
        uint_t v = *(const uint_t*)&Yb[(size_t)sorted_src[k] * 64 + l * 2];
        a0 += bf16lo(v);
        a1 += bf16hi(v);
    }
    float inv = 1.0f / fmaxf((float)(s1 - s0), 1.0f);
    uint_t z = *(const uint_t*)&Zb[(size_t)node * 64 + l * 2];
    float2 bb = *(const float2*)&bias[l * 2];
    float v0 = bf16lo(z) + a0 * inv + bb.x;
    float v1 = bf16hi(z) + a1 * inv + bb.y;
    float m = fmaxf(v0, v1);
#pragma unroll
    for (int off = 16; off; off >>= 1) m = fmaxf(m, __shfl_xor(m, off));
    float s = expf(v0 - m) + expf(v1 - m);
#pragma unroll
    for (int off = 16; off; off >>= 1) s += __shfl_xor(s, off);
    float ls = logf(s);
    f32x2 o;
    o[0] = v0 - m - ls;
    o[1] = v1 - m - ls;
    __builtin_nontemporal_store(o, (f32x2*)&out[(size_t)node * 64 + l * 2]);
}

// ---------------- BatchNorm stats: two-stage column reduction (bf16 input) ----------------

__global__ __launch_bounds__(256) void bn_part_kernel(const ushort_t* __restrict__ Hb,
                                                      float* __restrict__ P, int M) {
    int b = blockIdx.x;
    int R = (M + NB_PART - 1) / NB_PART;
    int r0 = b * R, r1 = min(r0 + R, M);
    int colg = (threadIdx.x & 15) * 8;
    int rowoff = threadIdx.x >> 4;
    float s[8], s2[8];
#pragma unroll
    for (int j = 0; j < 8; j++) { s[j] = 0.f; s2[j] = 0.f; }
    for (int r = r0 + rowoff; r < r1; r += 16) {
        u32x4 v = __builtin_nontemporal_load((const u32x4*)&Hb[(size_t)r * 128 + colg]);
#pragma unroll
        for (int q = 0; q < 4; q++) {
            float flo = bf16lo(v[q]);
            float fhi = bf16hi(v[q]);
            s[2 * q] += flo;
            s2[2 * q] += flo * flo;
            s[2 * q + 1] += fhi;
            s2[2 * q + 1] += fhi * fhi;
        }
    }
    __shared__ float ls[256][16];
#pragma unroll
    for (int j = 0; j < 8; j++) {
        ls[threadIdx.x][j] = s[j];
        ls[threadIdx.x][8 + j] = s2[j];
    }
    __syncthreads();
    if (threadIdx.x < 128) {
        int g = threadIdx.x >> 3, j = threadIdx.x & 7;
        float a = 0.f, c = 0.f;
#pragma unroll
        for (int kk = 0; kk < 16; kk++) {
            int id = kk * 16 + g;
            a += ls[id][j];
            c += ls[id][8 + j];
        }
        P[(size_t)b * 256 + threadIdx.x] = a;
        P[(size_t)b * 256 + 128 + threadIdx.x] = c;
    }
}

__global__ __launch_bounds__(1024) void bn_reduce_kernel(const float* __restrict__ P,
                                                         float* __restrict__ stats) {
    int c = threadIdx.x & 255, q = threadIdx.x >> 8;
    float acc = 0.f;
#pragma unroll 8
    for (int i = q * (NB_PART / 4); i < (q + 1) * (NB_PART / 4); i++)
        acc += P[(size_t)i * 256 + c];
    __shared__ float ls[4][256];
    ls[q][c] = acc;
    __syncthreads();
    if (threadIdx.x < 256) stats[c] = ls[0][c] + ls[1][c] + ls[2][c] + ls[3][c];
}

// ---------------- launch ----------------

extern "C" void kernel_launch(void* const* d_in, const int* in_sizes, int n_in,
                              void* d_out, int out_size, void* d_ws, size_t ws_size,
                              hipStream_t stream) {
    const float* x   = (const float*)d_in[0];
    const int*   ei  = (const int*)d_in[1];
    const float* Wl0 = (const float*)d_in[2];
    const float* Wr0 = (const float*)d_in[3];
    const float* b0  = (const float*)d_in[4];
    const float* g0  = (const float*)d_in[5];
    const float* be0 = (const float*)d_in[6];
    const float* Wl1 = (const float*)d_in[7];
    const float* Wr1 = (const float*)d_in[8];
    const float* b1  = (const float*)d_in[9];
    const float* g1  = (const float*)d_in[10];
    const float* be1 = (const float*)d_in[11];
    const float* Wl2 = (const float*)d_in[12];
    const float* Wr2 = (const float*)d_in[13];
    const float* b2  = (const float*)d_in[14];

    const int N = in_sizes[0] / D_IN;   // 50000
    const int E = in_sizes[1] / 2;      // 800000
    const int PB = (N + 255) / 256;     // 196

    // workspace layout (all bf16 node buffers)
    ushort_t* Hb = (ushort_t*)d_ws;                        // N*128 bf16
    ushort_t* Zb = Hb + (size_t)N * D_IN;                  // N*128 bf16 (layer2: N*64)
    ushort_t* Yb = Zb + (size_t)N * D_IN;                  // N*128 bf16
    int* cnt    = (int*)(Yb + (size_t)N * D_IN);
    int* offs   = cnt + N;
    int* cursor = offs + N + 1;
    int* bsum   = cursor + N;
    int* bpre   = bsum + 256;
    ushort_t* sorted = (ushort_t*)(bpre + 256);            // E ushort
    float* stats = (float*)(sorted + E + (E & 1));         // 512 f32 (2 layers)
    float* P = stats + 512;                                // NB_PART*256 f32
    short* WlF0 = (short*)(P + NB_PART * 256);
    short* WrF0 = WlF0 + 16384;
    short* WlF1 = WrF0 + 16384;
    short* WrF1 = WlF1 + 16384;
    short* WlF2 = WrF1 + 16384;
    short* WrF2 = WlF2 + 8192;

    const int eb = (E + 255) / 256;

    // ---- CSR build ----
    hipMemsetAsync(cnt, 0, (size_t)N * sizeof(int), stream);
    hist_kernel<<<eb, 256, 0, stream>>>(ei + E, cnt, E);
    scan_part_kernel<<<PB, 256, 0, stream>>>(cnt, bsum, N);
    scan_mid_kernel<<<1, 256, 0, stream>>>(bsum, bpre, offs, PB, N);
    scan_final_kernel<<<PB, 256, 0, stream>>>(cnt, bpre, offs, cursor, N);
    scatter_kernel<<<dim3(eb, 2), 256, 0, stream>>>(ei, ei + E, cursor, sorted, E, (N + 1) / 2);

    // ---- weight swizzle ----
    wswz_kernel<<<dim3(8, 2, 3), 256, 0, stream>>>(Wl0, Wr0, Wl1, Wr1, Wl2, Wr2,
                                                   WlF0, WrF0, WlF1, WrF1, WlF2, WrF2);

    const int gb = (N + 63) / 64;   // 782
    const int ab = (N + 7) / 8;     // 6250

    // ---- layer 0 ----
    gemm2_mfma<128, false><<<gb, 256, 0, stream>>>(x, WlF0, WrF0, Yb, Zb,
                                                   nullptr, nullptr, nullptr, N);
    agg128_kernel<<<ab, 256, 0, stream>>>(Yb, offs, sorted, b0, Zb, Hb, N);
    bn_part_kernel<<<NB_PART, 256, 0, stream>>>(Hb, P, N);
    bn_reduce_kernel<<<1, 1024, 0, stream>>>(P, stats);

    // ---- layer 1 ----
    gemm2_mfma<128, true><<<gb, 256, 0, stream>>>(Hb, WlF1, WrF1, Yb, Zb,
                                                  stats, g0, be0, N);
    agg128_kernel<<<ab, 256, 0, stream>>>(Yb, offs, sorted, b1, Zb, Hb, N);
    bn_part_kernel<<<NB_PART, 256, 0, stream>>>(Hb, P, N);
    bn_reduce_kernel<<<1, 1024, 0, stream>>>(P, stats + 256);

    // ---- layer 2 ----
    gemm2_mfma<64, true><<<gb, 128, 0, stream>>>(Hb, WlF2, WrF2, Yb, Zb,
                                                 stats + 256, g1, be1, N);
    agg_lsm_kernel<<<ab, 256, 0, stream>>>(Yb, offs, sorted, b2, Zb, (float*)d_out, N);
}